// Round 12
// baseline (393.892 us; speedup 1.0000x reference)
//
#include <hip/hip_runtime.h>

#define SEQ   2048
#define EMB   1024
#define NH    16
#define HD    64
#define BATCH 4

typedef __attribute__((ext_vector_type(8))) short short8;   // 8 bf16 = 4 VGPR
typedef __attribute__((ext_vector_type(4))) float floatx4;  // MFMA acc
typedef __attribute__((ext_vector_type(4))) uint uintx4;

// bf16 round-to-nearest-even (integer trick; bit-identical to v_cvt_pk RNE).
static __device__ __forceinline__ ushort f2bf_rne(float x) {
  unsigned u = __float_as_uint(x);
  unsigned r = u + 0x7FFFu + ((u >> 16) & 1u);
  return (ushort)(r >> 16);
}
static __device__ __forceinline__ float bf2f(ushort h) {
  return __uint_as_float(((unsigned)h) << 16);
}

// HW packed f32->bf16 RNE: dst = bf16(a) | bf16(b)<<16  (1 VALU op).
static __device__ __forceinline__ uint pk_bf16(float a, float b) {
  uint r;
  asm("v_cvt_pk_bf16_f32 %0, %1, %2" : "=v"(r) : "v"(a), "v"(b));
  return r;
}
// Split two floats into packed hi and packed lo words (~6 ops/pair).
static __device__ __forceinline__ void split_pair(float a, float b, uint& h,
                                                  uint& l) {
  h = pk_bf16(a, b);
  const float ha = __uint_as_float(h << 16);
  const float hb = __uint_as_float(h & 0xFFFF0000u);
  l = pk_bf16(a - ha, b - hb);
}

// Async global->LDS, 16 bytes per lane. LDS dest must be wave-uniform base
// (+ lane*16 implicit); global src is per-lane.
static __device__ __forceinline__ void load16(const void* g, void* l) {
  __builtin_amdgcn_global_load_lds(
      (const __attribute__((address_space(1))) unsigned int*)g,
      (__attribute__((address_space(3))) unsigned int*)l, 16, 0, 0);
}

// Swizzled LDS byte offset for a 128x32-ushort tile staged linearly.
static __device__ __forceinline__ int swz_off(int row, int kg) {
  return (row >> 1) * 128 + (((row & 1) << 2) + (kg ^ ((row >> 1) & 3))) * 16;
}

// Stage one 128x32-ushort tile (8 KB) from pre-split global [ld=EMB] via
// global_load_lds: per-lane INVERSE-swizzled source, linear LDS dest.
static __device__ __forceinline__ void stage_tile(const ushort* __restrict__ g,
                                                  int row0, int k0,
                                                  ushort* lds, int t) {
#pragma unroll
  for (int i = 0; i < 2; ++i) {
    const int slot = t + i * 256;            // 0..511
    const int line = slot >> 3, s = slot & 7;
    const int row = line * 2 + (s >> 2);
    const int c = (s & 3) ^ (line & 3);
    load16(g + (size_t)(row0 + row) * EMB + k0 + c * 8, lds + slot * 8);
  }
}

// ---------------------------------------------------------------------------
// fp32 -> hi/lo bf16 split converters for weight matrices.
// wconv3: Wq/Wk/Wv fused in one launch (512 blocks each).
// ---------------------------------------------------------------------------
__global__ __launch_bounds__(256) void wconv3_kernel(
    const float* __restrict__ Wq, const float* __restrict__ Wk,
    const float* __restrict__ Wv, ushort* __restrict__ Yqh,
    ushort* __restrict__ Yql, ushort* __restrict__ Ykh,
    ushort* __restrict__ Ykl, ushort* __restrict__ Yvh,
    ushort* __restrict__ Yvl) {
  const int which = blockIdx.x >> 9;
  const int bid = blockIdx.x & 511;
  const float* W = which == 0 ? Wq : which == 1 ? Wk : Wv;
  ushort* Yh = which == 0 ? Yqh : which == 1 ? Ykh : Yvh;
  ushort* Yl = which == 0 ? Yql : which == 1 ? Ykl : Yvl;
  const int i = (bid * 256 + threadIdx.x) * 8;
  const float4 a = *(const float4*)(W + i);
  const float4 b = *(const float4*)(W + i + 4);
  const float xv[8] = {a.x, a.y, a.z, a.w, b.x, b.y, b.z, b.w};
  uintx4 H, L;
#pragma unroll
  for (int j = 0; j < 4; ++j) {
    uint h, l;
    split_pair(xv[2 * j], xv[2 * j + 1], h, l);
    H[j] = h;
    L[j] = l;
  }
  *(uintx4*)&Yh[i] = H;
  *(uintx4*)&Yl[i] = L;
}

__global__ __launch_bounds__(256) void wconv_kernel(const float* __restrict__ W,
                                                    ushort* __restrict__ Yh,
                                                    ushort* __restrict__ Yl) {
  const int i = (blockIdx.x * 256 + threadIdx.x) * 8;
  const float4 a = *(const float4*)(W + i);
  const float4 b = *(const float4*)(W + i + 4);
  const float xv[8] = {a.x, a.y, a.z, a.w, b.x, b.y, b.z, b.w};
  uintx4 H, L;
#pragma unroll
  for (int j = 0; j < 4; ++j) {
    uint h, l;
    split_pair(xv[2 * j], xv[2 * j + 1], h, l);
    H[j] = h;
    L[j] = l;
  }
  *(uintx4*)&Yh[i] = H;
  *(uintx4*)&Yl[i] = L;
}

// ---------------------------------------------------------------------------
// Split-bf16 projection GEMM: Y = X @ W^T + bias.
// Round 12: for PREB && !PREA (QKV projs), A-staging is T14-split:
//   load X(k+1) fp32 -> REGS at step start (latency hides under MFMA),
//   computeStep issues its ds_reads, THEN convert+ds_write regs -> buf^1
//   (writes overlap MFMA execution; __syncthreads' lgkmcnt(0) covers them).
// PREA && PREB (O-proj): both operands via async gload_lds, 2-phase dbuf.
// Tier-C (!PREA && !PREB): legacy single-buffer.
// ---------------------------------------------------------------------------
template <int MODE, bool PREA, bool PREB>
__global__ __launch_bounds__(256) void proj_mfma_kernel(
    const float* __restrict__ X, const ushort* __restrict__ Xh,
    const ushort* __restrict__ Xl, const float* __restrict__ W,
    const ushort* __restrict__ Wh, const ushort* __restrict__ Wl,
    const float* __restrict__ bias, float* __restrict__ Yf,
    ushort* __restrict__ Yh, ushort* __restrict__ Yl) {
  constexpr bool DBUF = (PREA || PREB);
  constexpr int NB = DBUF ? 2 : 1;
  constexpr int ASZ = PREA ? 128 * 32 : 128 * 40;
  constexpr int BSZ = PREB ? 128 * 32 : 128 * 40;
  __shared__ ushort Ahi[NB][ASZ], Alo[NB][ASZ];
  __shared__ ushort Bhi[NB][BSZ], Blo[NB][BSZ];

  const int t = threadIdx.x;
  const int lane = t & 63, wave = t >> 6;
  const int m0 = blockIdx.y * 128, n0 = blockIdx.x * 128;
  const int wm = (wave >> 1) * 64, wn = (wave & 1) * 64;
  const int fr = lane & 15, kg = lane >> 4;

  floatx4 acc[4][4];
#pragma unroll
  for (int i = 0; i < 4; ++i)
#pragma unroll
    for (int j = 0; j < 4; ++j)
#pragma unroll
      for (int r = 0; r < 4; ++r) acc[i][j][r] = 0.f;

  auto stageB = [&](int k0, int b) {
    if constexpr (PREB) {
      stage_tile(Wh, n0, k0, Bhi[b], t);
      stage_tile(Wl, n0, k0, Blo[b], t);
    } else {
#pragma unroll
      for (int i = 0; i < 4; ++i) {
        const int f = t + 256 * i;
        const int row = f >> 3, kq = f & 7;
        const float4 v =
            *(const float4*)(W + (size_t)(n0 + row) * EMB + k0 + kq * 4);
        uint h0, l0, h1, l1;
        split_pair(v.x, v.y, h0, l0);
        split_pair(v.z, v.w, h1, l1);
        uint2 hp, lp;
        hp.x = h0; hp.y = h1;
        lp.x = l0; lp.y = l1;
        *(uint2*)&Bhi[b][row * 40 + kq * 4] = hp;
        *(uint2*)&Blo[b][row * 40 + kq * 4] = lp;
      }
    }
  };
  auto loadA_regs = [&](int k0, float4* xr) {
#pragma unroll
    for (int i = 0; i < 4; ++i) {
      const int f = t + 256 * i;
      const int row = f >> 3, kq = f & 7;
      xr[i] = *(const float4*)(X + (size_t)(m0 + row) * EMB + k0 + kq * 4);
    }
  };
  auto writeA_regs = [&](const float4* xr, int b) {
#pragma unroll
    for (int i = 0; i < 4; ++i) {
      const int f = t + 256 * i;
      const int row = f >> 3, kq = f & 7;
      uint h0, l0, h1, l1;
      split_pair(xr[i].x, xr[i].y, h0, l0);
      split_pair(xr[i].z, xr[i].w, h1, l1);
      uint2 hp, lp;
      hp.x = h0; hp.y = h1;
      lp.x = l0; lp.y = l1;
      *(uint2*)&Ahi[b][row * 40 + kq * 4] = hp;
      *(uint2*)&Alo[b][row * 40 + kq * 4] = lp;
    }
  };
  auto stageA_pre = [&](int k0, int b) {
    if constexpr (PREA) {
      stage_tile(Xh, m0, k0, Ahi[b], t);
      stage_tile(Xl, m0, k0, Alo[b], t);
    }
  };
  auto computeStep = [&](int cur) {
    short8 bhv[4], blv[4];
#pragma unroll
    for (int nf = 0; nf < 4; ++nf) {
      const int row = wn + nf * 16 + fr;
      if constexpr (PREB) {
        const int off = swz_off(row, kg);
        bhv[nf] = *(const short8*)((const char*)Bhi[cur] + off);
        blv[nf] = *(const short8*)((const char*)Blo[cur] + off);
      } else {
        bhv[nf] = *(const short8*)&Bhi[cur][row * 40 + kg * 8];
        blv[nf] = *(const short8*)&Blo[cur][row * 40 + kg * 8];
      }
    }
#pragma unroll
    for (int mf = 0; mf < 4; ++mf) {
      const int arow = wm + mf * 16 + fr;
      short8 ah, al;
      if constexpr (PREA) {
        const int off = swz_off(arow, kg);
        ah = *(const short8*)((const char*)Ahi[cur] + off);
        al = *(const short8*)((const char*)Alo[cur] + off);
      } else {
        ah = *(const short8*)&Ahi[cur][arow * 40 + kg * 8];
        al = *(const short8*)&Alo[cur][arow * 40 + kg * 8];
      }
#pragma unroll
      for (int nf = 0; nf < 4; ++nf) {
        acc[mf][nf] = __builtin_amdgcn_mfma_f32_16x16x32_bf16(ah, bhv[nf],
                                                              acc[mf][nf], 0, 0, 0);
        acc[mf][nf] = __builtin_amdgcn_mfma_f32_16x16x32_bf16(ah, blv[nf],
                                                              acc[mf][nf], 0, 0, 0);
        acc[mf][nf] = __builtin_amdgcn_mfma_f32_16x16x32_bf16(al, bhv[nf],
                                                              acc[mf][nf], 0, 0, 0);
      }
    }
  };

  if constexpr (PREA && PREB) {
    stageB(0, 0);
    stageA_pre(0, 0);
    asm volatile("s_waitcnt vmcnt(0)");
    __syncthreads();
#pragma unroll 1
    for (int k0 = 0; k0 < EMB; k0 += 32) {
      const int cur = (k0 >> 5) & 1;
      if (k0 + 32 < EMB) {
        stageB(k0 + 32, cur ^ 1);
        stageA_pre(k0 + 32, cur ^ 1);
      }
      computeStep(cur);
      asm volatile("s_waitcnt vmcnt(0)");
      __syncthreads();
    }
  } else if constexpr (PREB) {
    // QKV projs: B async; A via reg-load early / convert-write late (T14).
    stageB(0, 0);
    {
      float4 xr0[4];
      loadA_regs(0, xr0);
      writeA_regs(xr0, 0);
    }
    asm volatile("s_waitcnt vmcnt(0)");
    __syncthreads();
#pragma unroll 1
    for (int k0 = 0; k0 < EMB; k0 += 32) {
      const int cur = (k0 >> 5) & 1;
      const bool more = (k0 + 32 < EMB);
      float4 xr[4];
      if (more) {
        loadA_regs(k0 + 32, xr);   // global loads issue; hide under compute
        stageB(k0 + 32, cur ^ 1);  // async gload_lds, vmcnt-counted
      }
      computeStep(cur);            // ds_reads of buf[cur] issue first
      if (more) writeA_regs(xr, cur ^ 1);  // ds_writes overlap MFMA exec
      asm volatile("s_waitcnt vmcnt(0)");
      __syncthreads();
    }
  } else {
#pragma unroll 1
    for (int k0 = 0; k0 < EMB; k0 += 32) {
      __syncthreads();
      stageB(k0, 0);
      {
        float4 xr0[4];
        loadA_regs(k0, xr0);
        writeA_regs(xr0, 0);
      }
      __syncthreads();
      computeStep(0);
    }
  }

  // ---- epilogue: C/D layout col = lane&15, row = (lane>>4)*4 + reg ----
  const int rg = lane >> 4;
#pragma unroll
  for (int nf = 0; nf < 4; ++nf) {
    const int n = n0 + wn + nf * 16 + fr;
    const float bb = bias[n];
    if (MODE == 2) {
      const int hh = n >> 6, d = n & 63;
#pragma unroll
      for (int mf = 0; mf < 4; ++mf) {
        const int mb = m0 + wm + mf * 16 + rg * 4;
        const int b = mb >> 11, s = mb & (SEQ - 1);
        uint h0, l0, h1, l1;
        split_pair(acc[mf][nf][0] + bb, acc[mf][nf][1] + bb, h0, l0);
        split_pair(acc[mf][nf][2] + bb, acc[mf][nf][3] + bb, h1, l1);
        uint2 hp, lp;
        hp.x = h0; hp.y = h1;
        lp.x = l0; lp.y = l1;
        const int idx = (b * NH + hh) * (HD * SEQ) + d * SEQ + s;
        *(uint2*)&Yh[idx] = hp;
        *(uint2*)&Yl[idx] = lp;
      }
    } else {
#pragma unroll
      for (int mf = 0; mf < 4; ++mf) {
#pragma unroll
        for (int r = 0; r < 4; ++r) {
          const int m = m0 + wm + mf * 16 + rg * 4 + r;
          float val = acc[mf][nf][r] + bb;
          if (MODE == 3) {
            Yf[(size_t)m * EMB + n] = val;
          } else {
            if (MODE == 0) val *= 0.125f;  // fold 1/sqrt(64) into Q
            const int hh = n >> 6, d = n & 63;
            const int b = m >> 11, s = m & (SEQ - 1);
            const int idx = ((b * NH + hh) * SEQ + s) * HD + d;
            const ushort h = f2bf_rne(val);
            Yh[idx] = h;
            Yl[idx] = f2bf_rne(val - bf2f(h));
          }
        }
      }
    }
  }
}

// ---------------------------------------------------------------------------
// Split-bf16 MFMA causal flash attention — swapped QK^T + permuted K rows
// (P stays in registers), causal pair-balancing, K/V LDS double-buffer,
// cvt_pk P-pack (T12), defer-max THR=8 (T13). Round 12: setprio REVERTED
// (T5 regime mismatch: barrier-lockstep structure; r11 measured -6us).
// ---------------------------------------------------------------------------
template <bool SPLITOUT>
__global__ __launch_bounds__(256, 2) void attn_mfma_kernel(
    const ushort* __restrict__ Qh, const ushort* __restrict__ Ql,
    const ushort* __restrict__ Kh, const ushort* __restrict__ Kl,
    const ushort* __restrict__ Vth, const ushort* __restrict__ Vtl,
    float* __restrict__ O, ushort* __restrict__ Oh, ushort* __restrict__ Ol) {
  __shared__ __align__(16) ushort KHs[2][64 * 64], KLs[2][64 * 64];
  __shared__ __align__(16) ushort VHs[2][64 * 64], VLs[2][64 * 64];  // 64 KB

  const int bh = blockIdx.x;
  const int qtA = blockIdx.y;  // 0..7, paired with qtB = 15 - qtA
  const int qtB = 15 - qtA;
  const int t = threadIdx.x;
  const int lane = t & 63, wave = t >> 6;
  const int fr = lane & 15, kg = lane >> 4;
  const int base = bh * (SEQ * HD);  // same for [bh,s,d] and [bh,d,s]
  const int r8 = lane >> 3, c8 = lane & 7;

  const int q00[2] = {qtA * 128 + wave * 32, qtB * 128 + wave * 32};
  const int ext[2] = {(q00[0] + 95) >> 6, (q00[1] + 95) >> 6};
  const int nkt = 2 * qtB + 2;  // block-level tile count (= max ext)

  // ---- Q fragments for both q-groups (already scaled + split) ----
  short8 qfh[2][2][2], qfl[2][2][2];  // [grp][mf][ks]
#pragma unroll
  for (int g = 0; g < 2; ++g)
#pragma unroll
    for (int mf = 0; mf < 2; ++mf)
#pragma unroll
      for (int ks = 0; ks < 2; ++ks) {
        const int idx = base + (q00[g] + mf * 16 + fr) * HD + ks * 32 + kg * 8;
        qfh[g][mf][ks] = *(const short8*)&Qh[idx];
        qfl[g][mf][ks] = *(const short8*)&Ql[idx];
      }

  floatx4 oacc[2][2][4];  // [grp][mf][nf]
  float m_run[2][2], l_run[2][2];
#pragma unroll
  for (int g = 0; g < 2; ++g)
#pragma unroll
    for (int mf = 0; mf < 2; ++mf) {
#pragma unroll
      for (int nf = 0; nf < 4; ++nf)
#pragma unroll
        for (int r = 0; r < 4; ++r) oacc[g][mf][nf][r] = 0.f;
      m_run[g][mf] = -INFINITY;
      l_run[g][mf] = 0.f;
    }

  // stage tile kt into buffer b (8 gll per wave; src-swizzled, linear dest)
  auto stage = [&](int kt, int b) {
#pragma unroll
    for (int i = 0; i < 2; ++i) {
      const int lrow = wave * 16 + i * 8;
      const int row = lrow + r8;               // kv-row / d-row, 0..63
      const int sw = (c8 ^ (row & 7)) << 3;    // swizzled bf16 offset in row
      const int gk = base + (kt * 64 + row) * HD + sw;
      const int gv = base + row * SEQ + kt * 64 + sw;
      load16(Kh + gk, (char*)KHs + b * 8192 + lrow * 128);
      load16(Kl + gk, (char*)KLs + b * 8192 + lrow * 128);
      load16(Vth + gv, (char*)VHs + b * 8192 + lrow * 128);
      load16(Vtl + gv, (char*)VLs + b * 8192 + lrow * 128);
    }
  };

  stage(0, 0);
  asm volatile("s_waitcnt vmcnt(0)");
  __syncthreads();

#pragma unroll 1
  for (int kt = 0; kt < nkt; ++kt) {
    const int cur = kt & 1;
    if (kt + 1 < nkt) stage(kt + 1, cur ^ 1);  // prefetch overlaps compute
    const int c0 = kt * 64;
    const int kb = cur * 8192;  // byte offset of current buffer

#pragma unroll
    for (int g = 0; g < 2; ++g) {
      if (kt < ext[g]) {
        const int q0 = q00[g];

        // ---- S^T = K_perm Q (split-bf16, 3 MFMA) ----
        floatx4 s2[2][4];
#pragma unroll
        for (int mf = 0; mf < 2; ++mf)
#pragma unroll
          for (int nf = 0; nf < 4; ++nf)
#pragma unroll
            for (int r = 0; r < 4; ++r) s2[mf][nf][r] = 0.f;

#pragma unroll
        for (int ksd = 0; ksd < 2; ++ksd)
#pragma unroll
          for (int nf = 0; nf < 4; ++nf) {
            const int kr =
                32 * (nf >> 1) + 8 * (fr >> 2) + 4 * (nf & 1) + (fr & 3);
            const int byo = kb + kr * 128 + (((ksd * 4 + kg) ^ (kr & 7)) << 4);
            const short8 kh = *(const short8*)((const char*)KHs + byo);
            const short8 kl = *(const short8*)((const char*)KLs + byo);
#pragma unroll
            for (int mf = 0; mf < 2; ++mf) {
              s2[mf][nf] = __builtin_amdgcn_mfma_f32_16x16x32_bf16(
                  kh, qfh[g][mf][ksd], s2[mf][nf], 0, 0, 0);
              s2[mf][nf] = __builtin_amdgcn_mfma_f32_16x16x32_bf16(
                  kh, qfl[g][mf][ksd], s2[mf][nf], 0, 0, 0);
              s2[mf][nf] = __builtin_amdgcn_mfma_f32_16x16x32_bf16(
                  kl, qfh[g][mf][ksd], s2[mf][nf], 0, 0, 0);
            }
          }

        // ---- causal mask (edge tiles only); col from permuted mapping ----
        if (c0 + 63 > q0) {
#pragma unroll
          for (int mf = 0; mf < 2; ++mf)
#pragma unroll
            for (int nf = 0; nf < 4; ++nf)
#pragma unroll
              for (int r = 0; r < 4; ++r) {
                const int col =
                    c0 + 32 * (nf >> 1) + 8 * kg + 4 * (nf & 1) + r;
                const int row = q0 + mf * 16 + fr;
                if (col > row) s2[mf][nf][r] = -1e9f;
              }
        }

        // ---- online softmax with defer-max (THR=8, wave-uniform vote) ----
        float pmv[2];
#pragma unroll
        for (int mf = 0; mf < 2; ++mf) {
          float pm = s2[mf][0][0];
#pragma unroll
          for (int nf = 0; nf < 4; ++nf)
#pragma unroll
            for (int r = 0; r < 4; ++r) pm = fmaxf(pm, s2[mf][nf][r]);
          pm = fmaxf(pm, __shfl_xor(pm, 16));
          pm = fmaxf(pm, __shfl_xor(pm, 32));
          pmv[mf] = pm;
        }
        float alpha2[2] = {1.f, 1.f};
        const bool grow = !__all((pmv[0] <= m_run[g][0] + 8.f) &&
                                 (pmv[1] <= m_run[g][1] + 8.f));
        if (grow) {
#pragma unroll
          for (int mf = 0; mf < 2; ++mf) {
            const float mnew = fmaxf(m_run[g][mf], pmv[mf]);
            alpha2[mf] = __expf(m_run[g][mf] - mnew);
            m_run[g][mf] = mnew;
          }
          // rescale oacc (alpha redistributed to C/D row owners)
#pragma unroll
          for (int mf = 0; mf < 2; ++mf)
#pragma unroll
            for (int r = 0; r < 4; ++r) {
              const float a = __shfl(alpha2[mf], (kg * 4 + r) | (lane & 48));
#pragma unroll
              for (int nf = 0; nf < 4; ++nf) oacc[g][mf][nf][r] *= a;
            }
        }
#pragma unroll
        for (int mf = 0; mf < 2; ++mf) {
          const float mm = m_run[g][mf];
          float sum = 0.f;
#pragma unroll
          for (int nf = 0; nf < 4; ++nf)
#pragma unroll
            for (int r = 0; r < 4; ++r) {
              const float p = __expf(s2[mf][nf][r] - mm);
              s2[mf][nf][r] = p;
              sum += p;
            }
          sum += __shfl_xor(sum, 16);
          sum += __shfl_xor(sum, 32);
          l_run[g][mf] = l_run[g][mf] * alpha2[mf] + sum;
        }

        // ---- pack P into PV A-fragments via v_cvt_pk_bf16_f32 (T12) ----
        short8 pah[2][2], pal[2][2];
#pragma unroll
        for (int mf = 0; mf < 2; ++mf)
#pragma unroll
          for (int ks = 0; ks < 2; ++ks) {
            uintx4 H, L;
#pragma unroll
            for (int jj = 0; jj < 4; ++jj) {
              const int nfi = 2 * ks + (jj >> 1);
              uint h, l;
              split_pair(s2[mf][nfi][(2 * jj) & 3], s2[mf][nfi][(2 * jj + 1) & 3],
                         h, l);
              H[jj] = h;
              L[jj] = l;
            }
            pah[mf][ks] = *(short8*)&H;
            pal[mf][ks] = *(short8*)&L;
          }

        // ---- O += P V (split-bf16), V^T frags from swizzled LDS ----
#pragma unroll
        for (int ks = 0; ks < 2; ++ks)
#pragma unroll
          for (int nf = 0; nf < 4; ++nf) {
            const int d = nf * 16 + fr;
            const int byo = kb + d * 128 + (((ks * 4 + kg) ^ (d & 7)) << 4);
            const short8 vh = *(const short8*)((const char*)VHs + byo);
            const short8 vl = *(const short8*)((const char*)VLs + byo);
#pragma unroll
            for (int mf = 0; mf < 2; ++mf) {
              oacc[g][mf][nf] = __builtin_amdgcn_mfma_f32_16x16x32_bf16(
                  pah[mf][ks], vh, oacc[g][mf][nf], 0, 0, 0);
              oacc[g][mf][nf] = __builtin_amdgcn_mfma_f32_16x16x32_bf16(
                  pah[mf][ks], vl, oacc[g][mf][nf], 0, 0, 0);
              oacc[g][mf][nf] = __builtin_amdgcn_mfma_f32_16x16x32_bf16(
                  pal[mf][ks], vh, oacc[g][mf][nf], 0, 0, 0);
            }
          }
      }
    }

    asm volatile("s_waitcnt vmcnt(0)");  // next-tile stage complete
    __syncthreads();
  }

  // ---- epilogue: AO[m = b*SEQ+s][e = h*64+d]; l redistributed like alpha ----
  const int b = bh >> 4, hsel = bh & 15;
#pragma unroll
  for (int g = 0; g < 2; ++g)
#pragma unroll
    for (int mf = 0; mf < 2; ++mf)
#pragma unroll
      for (int r = 0; r < 4; ++r) {
        const float lv = __shfl(l_run[g][mf], (kg * 4 + r) | (lane & 48));
        const float inv = 1.f / lv;
        const int grow2 = q00[g] + mf * 16 + kg * 4 + r;
        const int rowbase = (b * SEQ + grow2) * EMB + hsel * HD;
#pragma unroll
        for (int nf = 0; nf < 4; ++nf) {
          const float val = oacc[g][mf][nf][r] * inv;
          const int idx = rowbase + nf * 16 + fr;
          if constexpr (SPLITOUT) {
            const ushort hh = f2bf_rne(val);
            Oh[idx] = hh;
            Ol[idx] = f2bf_rne(val - bf2f(hh));
          } else {
            O[idx] = val;
          }
        }
      }
}

// ---------------------------------------------------------------------------
extern "C" void kernel_launch(void* const* d_in, const int* in_sizes, int n_in,
                              void* d_out, int out_size, void* d_ws,
                              size_t ws_size, hipStream_t stream) {
  const float* q = (const float*)d_in[0];
  const float* k = (const float*)d_in[1];
  const float* v = (const float*)d_in[2];
  // d_in[3] = causal mask (tril by construction) -> predicate col>row instead
  const float* Wq = (const float*)d_in[4];
  const float* bq = (const float*)d_in[5];
  const float* Wk = (const float*)d_in[6];
  const float* bk = (const float*)d_in[7];
  const float* Wv = (const float*)d_in[8];
  const float* bv = (const float*)d_in[9];
  const float* Wo = (const float*)d_in[10];
  const float* bo = (const float*)d_in[11];
  float* out = (float*)d_out;

  const size_t E = (size_t)BATCH * SEQ * EMB;  // 8388608 elements
  const size_t WE = (size_t)EMB * EMB;         // 1048576 elements
  ushort* us = (ushort*)d_ws;
  ushort* Qh = us;
  ushort* Ql = us + E;
  ushort* Kh = us + 2 * E;
  ushort* Kl = us + 3 * E;
  ushort* Vth = us + 4 * E;
  ushort* Vtl = us + 5 * E;

  const dim3 pgrid(EMB / 128, (BATCH * SEQ) / 128);  // (8, 64)
  const dim3 agrid(BATCH * NH, 8);                   // paired q-tiles
  const dim3 blk(256);
  const int wgrid = (int)(WE / 8 / 256);  // 512 blocks per weight matrix

  if (ws_size >= 8 * E * sizeof(ushort)) {
    // ---- Tier A (ws >= 134.2 MB) ----
    ushort* W3 = us + 6 * E;
    ushort* Wqh = W3, *Wql = W3 + WE;
    ushort* Wkh = W3 + 2 * WE, *Wkl = W3 + 3 * WE;
    ushort* Wvh = W3 + 4 * WE, *Wvl = W3 + 5 * WE;
    ushort* AOh = us + 6 * E, *AOl = us + 7 * E;  // overwrites W3 post-projs
    ushort* Woh = us, *Wol = us + WE;             // Qh region, dead post-attn

    wconv3_kernel<<<3 * wgrid, blk, 0, stream>>>(Wq, Wk, Wv, Wqh, Wql, Wkh,
                                                 Wkl, Wvh, Wvl);
    proj_mfma_kernel<0, false, true><<<pgrid, blk, 0, stream>>>(
        q, nullptr, nullptr, nullptr, Wqh, Wql, bq, nullptr, Qh, Ql);
    proj_mfma_kernel<1, false, true><<<pgrid, blk, 0, stream>>>(
        k, nullptr, nullptr, nullptr, Wkh, Wkl, bk, nullptr, Kh, Kl);
    proj_mfma_kernel<2, false, true><<<pgrid, blk, 0, stream>>>(
        v, nullptr, nullptr, nullptr, Wvh, Wvl, bv, nullptr, Vth, Vtl);
    attn_mfma_kernel<true><<<agrid, blk, 0, stream>>>(Qh, Ql, Kh, Kl, Vth, Vtl,
                                                      nullptr, AOh, AOl);
    wconv_kernel<<<wgrid, blk, 0, stream>>>(Wo, Woh, Wol);
    proj_mfma_kernel<3, true, true><<<pgrid, blk, 0, stream>>>(
        nullptr, AOh, AOl, nullptr, Woh, Wol, bo, out, nullptr, nullptr);
  } else if (ws_size >= (6 * E + 6 * WE) * sizeof(ushort)) {
    // ---- Tier B (ws >= 113.3 MB): AO hi/lo lives in `out` ----
    ushort* W3 = us + 6 * E;
    ushort* Wqh = W3, *Wql = W3 + WE;
    ushort* Wkh = W3 + 2 * WE, *Wkl = W3 + 3 * WE;
    ushort* Wvh = W3 + 4 * WE, *Wvl = W3 + 5 * WE;
    ushort* AOh = (ushort*)d_out, *AOl = AOh + E;
    ushort* Woh = us, *Wol = us + WE;
    float* PO = (float*)(us + 2 * E);

    wconv3_kernel<<<3 * wgrid, blk, 0, stream>>>(Wq, Wk, Wv, Wqh, Wql, Wkh,
                                                 Wkl, Wvh, Wvl);
    proj_mfma_kernel<0, false, true><<<pgrid, blk, 0, stream>>>(
        q, nullptr, nullptr, nullptr, Wqh, Wql, bq, nullptr, Qh, Ql);
    proj_mfma_kernel<1, false, true><<<pgrid, blk, 0, stream>>>(
        k, nullptr, nullptr, nullptr, Wkh, Wkl, bk, nullptr, Kh, Kl);
    proj_mfma_kernel<2, false, true><<<pgrid, blk, 0, stream>>>(
        v, nullptr, nullptr, nullptr, Wvh, Wvl, bv, nullptr, Vth, Vtl);
    attn_mfma_kernel<true><<<agrid, blk, 0, stream>>>(Qh, Ql, Kh, Kl, Vth, Vtl,
                                                      nullptr, AOh, AOl);
    wconv_kernel<<<wgrid, blk, 0, stream>>>(Wo, Woh, Wol);
    proj_mfma_kernel<3, true, true><<<pgrid, blk, 0, stream>>>(
        nullptr, AOh, AOl, nullptr, Woh, Wol, bo, PO, nullptr, nullptr);
    hipError_t e1 = hipMemcpyAsync(out, PO, E * sizeof(float),
                                   hipMemcpyDeviceToDevice, stream);
    (void)e1;
  } else {
    // ---- Tier C: in-kernel W conversion, fp32 AO (single-buffer legacy) ----
    float* AO = out;
    float* PO = (float*)d_ws;
    proj_mfma_kernel<0, false, false><<<pgrid, blk, 0, stream>>>(
        q, nullptr, nullptr, Wq, nullptr, nullptr, bq, nullptr, Qh, Ql);
    proj_mfma_kernel<1, false, false><<<pgrid, blk, 0, stream>>>(
        k, nullptr, nullptr, Wk, nullptr, nullptr, bk, nullptr, Kh, Kl);
    proj_mfma_kernel<2, false, false><<<pgrid, blk, 0, stream>>>(
        v, nullptr, nullptr, Wv, nullptr, nullptr, bv, nullptr, Vth, Vtl);
    attn_mfma_kernel<false><<<agrid, blk, 0, stream>>>(
        Qh, Ql, Kh, Kl, Vth, Vtl, AO, nullptr, nullptr);
    proj_mfma_kernel<3, false, false><<<pgrid, blk, 0, stream>>>(
        AO, nullptr, nullptr, Wo, nullptr, nullptr, bo, PO, nullptr, nullptr);
    hipError_t e2 = hipMemcpyAsync(out, PO, E * sizeof(float),
                                   hipMemcpyDeviceToDevice, stream);
    (void)e2;
  }
}

// Round 13
// 366.742 us; speedup vs baseline: 1.0740x; 1.0740x over previous
//
#include <hip/hip_runtime.h>

#define SEQ   2048
#define EMB   1024
#define NH    16
#define HD    64
#define BATCH 4

typedef __attribute__((ext_vector_type(8))) short short8;   // 8 bf16 = 4 VGPR
typedef __attribute__((ext_vector_type(4))) float floatx4;  // MFMA acc
typedef __attribute__((ext_vector_type(4))) uint uintx4;

// bf16 round-to-nearest-even (integer trick; bit-identical to v_cvt_pk RNE).
static __device__ __forceinline__ ushort f2bf_rne(float x) {
  unsigned u = __float_as_uint(x);
  unsigned r = u + 0x7FFFu + ((u >> 16) & 1u);
  return (ushort)(r >> 16);
}
static __device__ __forceinline__ float bf2f(ushort h) {
  return __uint_as_float(((unsigned)h) << 16);
}

// HW packed f32->bf16 RNE: dst = bf16(a) | bf16(b)<<16  (1 VALU op).
static __device__ __forceinline__ uint pk_bf16(float a, float b) {
  uint r;
  asm("v_cvt_pk_bf16_f32 %0, %1, %2" : "=v"(r) : "v"(a), "v"(b));
  return r;
}
// Split two floats into packed hi and packed lo words (~6 ops/pair).
static __device__ __forceinline__ void split_pair(float a, float b, uint& h,
                                                  uint& l) {
  h = pk_bf16(a, b);
  const float ha = __uint_as_float(h << 16);
  const float hb = __uint_as_float(h & 0xFFFF0000u);
  l = pk_bf16(a - ha, b - hb);
}

// Async global->LDS, 16 bytes per lane. LDS dest must be wave-uniform base
// (+ lane*16 implicit); global src is per-lane.
static __device__ __forceinline__ void load16(const void* g, void* l) {
  __builtin_amdgcn_global_load_lds(
      (const __attribute__((address_space(1))) unsigned int*)g,
      (__attribute__((address_space(3))) unsigned int*)l, 16, 0, 0);
}

// Swizzled LDS byte offset for a 128x32-ushort tile staged linearly.
static __device__ __forceinline__ int swz_off(int row, int kg) {
  return (row >> 1) * 128 + (((row & 1) << 2) + (kg ^ ((row >> 1) & 3))) * 16;
}

// Stage one 128x32-ushort tile (8 KB) from pre-split global [ld=EMB] via
// global_load_lds: per-lane INVERSE-swizzled source, linear LDS dest.
static __device__ __forceinline__ void stage_tile(const ushort* __restrict__ g,
                                                  int row0, int k0,
                                                  ushort* lds, int t) {
#pragma unroll
  for (int i = 0; i < 2; ++i) {
    const int slot = t + i * 256;            // 0..511
    const int line = slot >> 3, s = slot & 7;
    const int row = line * 2 + (s >> 2);
    const int c = (s & 3) ^ (line & 3);
    load16(g + (size_t)(row0 + row) * EMB + k0 + c * 8, lds + slot * 8);
  }
}

// ---------------------------------------------------------------------------
// fp32 -> hi/lo bf16 split converters for weight matrices.
// wconv3: Wq/Wk/Wv fused in one launch (512 blocks each).
// ---------------------------------------------------------------------------
__global__ __launch_bounds__(256) void wconv3_kernel(
    const float* __restrict__ Wq, const float* __restrict__ Wk,
    const float* __restrict__ Wv, ushort* __restrict__ Yqh,
    ushort* __restrict__ Yql, ushort* __restrict__ Ykh,
    ushort* __restrict__ Ykl, ushort* __restrict__ Yvh,
    ushort* __restrict__ Yvl) {
  const int which = blockIdx.x >> 9;
  const int bid = blockIdx.x & 511;
  const float* W = which == 0 ? Wq : which == 1 ? Wk : Wv;
  ushort* Yh = which == 0 ? Yqh : which == 1 ? Ykh : Yvh;
  ushort* Yl = which == 0 ? Yql : which == 1 ? Ykl : Yvl;
  const int i = (bid * 256 + threadIdx.x) * 8;
  const float4 a = *(const float4*)(W + i);
  const float4 b = *(const float4*)(W + i + 4);
  const float xv[8] = {a.x, a.y, a.z, a.w, b.x, b.y, b.z, b.w};
  uintx4 H, L;
#pragma unroll
  for (int j = 0; j < 4; ++j) {
    uint h, l;
    split_pair(xv[2 * j], xv[2 * j + 1], h, l);
    H[j] = h;
    L[j] = l;
  }
  *(uintx4*)&Yh[i] = H;
  *(uintx4*)&Yl[i] = L;
}

__global__ __launch_bounds__(256) void wconv_kernel(const float* __restrict__ W,
                                                    ushort* __restrict__ Yh,
                                                    ushort* __restrict__ Yl) {
  const int i = (blockIdx.x * 256 + threadIdx.x) * 8;
  const float4 a = *(const float4*)(W + i);
  const float4 b = *(const float4*)(W + i + 4);
  const float xv[8] = {a.x, a.y, a.z, a.w, b.x, b.y, b.z, b.w};
  uintx4 H, L;
#pragma unroll
  for (int j = 0; j < 4; ++j) {
    uint h, l;
    split_pair(xv[2 * j], xv[2 * j + 1], h, l);
    H[j] = h;
    L[j] = l;
  }
  *(uintx4*)&Yh[i] = H;
  *(uintx4*)&Yl[i] = L;
}

// ---------------------------------------------------------------------------
// Split-bf16 projection GEMM: Y = X @ W^T + bias.
// Round 13: REVERT to r11's proven dbuf schedule (T14 split regressed ~30us):
//   stage tile k+1 (async gload_lds for PRE operands; convert+ds_write for
//   fp32 operands) into buf^1 BEFORE computing tile k; one vmcnt(0)+barrier
//   per K-step. Tier-C (!PREA && !PREB): legacy single-buffer.
// ---------------------------------------------------------------------------
template <int MODE, bool PREA, bool PREB>
__global__ __launch_bounds__(256) void proj_mfma_kernel(
    const float* __restrict__ X, const ushort* __restrict__ Xh,
    const ushort* __restrict__ Xl, const float* __restrict__ W,
    const ushort* __restrict__ Wh, const ushort* __restrict__ Wl,
    const float* __restrict__ bias, float* __restrict__ Yf,
    ushort* __restrict__ Yh, ushort* __restrict__ Yl) {
  constexpr bool DBUF = (PREA || PREB);
  constexpr int NB = DBUF ? 2 : 1;
  constexpr int ASZ = PREA ? 128 * 32 : 128 * 40;
  constexpr int BSZ = PREB ? 128 * 32 : 128 * 40;
  __shared__ ushort Ahi[NB][ASZ], Alo[NB][ASZ];
  __shared__ ushort Bhi[NB][BSZ], Blo[NB][BSZ];

  const int t = threadIdx.x;
  const int lane = t & 63, wave = t >> 6;
  const int m0 = blockIdx.y * 128, n0 = blockIdx.x * 128;
  const int wm = (wave >> 1) * 64, wn = (wave & 1) * 64;
  const int fr = lane & 15, kg = lane >> 4;

  floatx4 acc[4][4];
#pragma unroll
  for (int i = 0; i < 4; ++i)
#pragma unroll
    for (int j = 0; j < 4; ++j)
#pragma unroll
      for (int r = 0; r < 4; ++r) acc[i][j][r] = 0.f;

  auto stageB = [&](int k0, int b) {
    if constexpr (PREB) {
      stage_tile(Wh, n0, k0, Bhi[b], t);
      stage_tile(Wl, n0, k0, Blo[b], t);
    } else {
#pragma unroll
      for (int i = 0; i < 4; ++i) {
        const int f = t + 256 * i;
        const int row = f >> 3, kq = f & 7;
        const float4 v =
            *(const float4*)(W + (size_t)(n0 + row) * EMB + k0 + kq * 4);
        uint h0, l0, h1, l1;
        split_pair(v.x, v.y, h0, l0);
        split_pair(v.z, v.w, h1, l1);
        uint2 hp, lp;
        hp.x = h0; hp.y = h1;
        lp.x = l0; lp.y = l1;
        *(uint2*)&Bhi[b][row * 40 + kq * 4] = hp;
        *(uint2*)&Blo[b][row * 40 + kq * 4] = lp;
      }
    }
  };
  auto stageA = [&](int k0, int b) {
    if constexpr (PREA) {
      stage_tile(Xh, m0, k0, Ahi[b], t);
      stage_tile(Xl, m0, k0, Alo[b], t);
    } else {
#pragma unroll
      for (int i = 0; i < 4; ++i) {
        const int f = t + 256 * i;
        const int row = f >> 3, kq = f & 7;
        const float4 v =
            *(const float4*)(X + (size_t)(m0 + row) * EMB + k0 + kq * 4);
        uint h0, l0, h1, l1;
        split_pair(v.x, v.y, h0, l0);
        split_pair(v.z, v.w, h1, l1);
        uint2 hp, lp;
        hp.x = h0; hp.y = h1;
        lp.x = l0; lp.y = l1;
        *(uint2*)&Ahi[b][row * 40 + kq * 4] = hp;
        *(uint2*)&Alo[b][row * 40 + kq * 4] = lp;
      }
    }
  };
  auto computeStep = [&](int cur) {
    short8 bhv[4], blv[4];
#pragma unroll
    for (int nf = 0; nf < 4; ++nf) {
      const int row = wn + nf * 16 + fr;
      if constexpr (PREB) {
        const int off = swz_off(row, kg);
        bhv[nf] = *(const short8*)((const char*)Bhi[cur] + off);
        blv[nf] = *(const short8*)((const char*)Blo[cur] + off);
      } else {
        bhv[nf] = *(const short8*)&Bhi[cur][row * 40 + kg * 8];
        blv[nf] = *(const short8*)&Blo[cur][row * 40 + kg * 8];
      }
    }
#pragma unroll
    for (int mf = 0; mf < 4; ++mf) {
      const int arow = wm + mf * 16 + fr;
      short8 ah, al;
      if constexpr (PREA) {
        const int off = swz_off(arow, kg);
        ah = *(const short8*)((const char*)Ahi[cur] + off);
        al = *(const short8*)((const char*)Alo[cur] + off);
      } else {
        ah = *(const short8*)&Ahi[cur][arow * 40 + kg * 8];
        al = *(const short8*)&Alo[cur][arow * 40 + kg * 8];
      }
#pragma unroll
      for (int nf = 0; nf < 4; ++nf) {
        acc[mf][nf] = __builtin_amdgcn_mfma_f32_16x16x32_bf16(ah, bhv[nf],
                                                              acc[mf][nf], 0, 0, 0);
        acc[mf][nf] = __builtin_amdgcn_mfma_f32_16x16x32_bf16(ah, blv[nf],
                                                              acc[mf][nf], 0, 0, 0);
        acc[mf][nf] = __builtin_amdgcn_mfma_f32_16x16x32_bf16(al, bhv[nf],
                                                              acc[mf][nf], 0, 0, 0);
      }
    }
  };

  if constexpr (DBUF) {
    stageB(0, 0);
    stageA(0, 0);
    asm volatile("s_waitcnt vmcnt(0)");
    __syncthreads();
#pragma unroll 1
    for (int k0 = 0; k0 < EMB; k0 += 32) {
      const int cur = (k0 >> 5) & 1;
      if (k0 + 32 < EMB) {  // prefetch next tile; loads overlap compute
        stageB(k0 + 32, cur ^ 1);
        stageA(k0 + 32, cur ^ 1);
      }
      computeStep(cur);
      asm volatile("s_waitcnt vmcnt(0)");
      __syncthreads();
    }
  } else {
#pragma unroll 1
    for (int k0 = 0; k0 < EMB; k0 += 32) {
      __syncthreads();
      stageB(k0, 0);
      stageA(k0, 0);
      __syncthreads();
      computeStep(0);
    }
  }

  // ---- epilogue: C/D layout col = lane&15, row = (lane>>4)*4 + reg ----
  const int rg = lane >> 4;
#pragma unroll
  for (int nf = 0; nf < 4; ++nf) {
    const int n = n0 + wn + nf * 16 + fr;
    const float bb = bias[n];
    if (MODE == 2) {
      const int hh = n >> 6, d = n & 63;
#pragma unroll
      for (int mf = 0; mf < 4; ++mf) {
        const int mb = m0 + wm + mf * 16 + rg * 4;
        const int b = mb >> 11, s = mb & (SEQ - 1);
        uint h0, l0, h1, l1;
        split_pair(acc[mf][nf][0] + bb, acc[mf][nf][1] + bb, h0, l0);
        split_pair(acc[mf][nf][2] + bb, acc[mf][nf][3] + bb, h1, l1);
        uint2 hp, lp;
        hp.x = h0; hp.y = h1;
        lp.x = l0; lp.y = l1;
        const int idx = (b * NH + hh) * (HD * SEQ) + d * SEQ + s;
        *(uint2*)&Yh[idx] = hp;
        *(uint2*)&Yl[idx] = lp;
      }
    } else {
#pragma unroll
      for (int mf = 0; mf < 4; ++mf) {
#pragma unroll
        for (int r = 0; r < 4; ++r) {
          const int m = m0 + wm + mf * 16 + rg * 4 + r;
          float val = acc[mf][nf][r] + bb;
          if (MODE == 3) {
            Yf[(size_t)m * EMB + n] = val;
          } else {
            if (MODE == 0) val *= 0.125f;  // fold 1/sqrt(64) into Q
            const int hh = n >> 6, d = n & 63;
            const int b = m >> 11, s = m & (SEQ - 1);
            const int idx = ((b * NH + hh) * SEQ + s) * HD + d;
            const ushort h = f2bf_rne(val);
            Yh[idx] = h;
            Yl[idx] = f2bf_rne(val - bf2f(h));
          }
        }
      }
    }
  }
}

// ---------------------------------------------------------------------------
// Split-bf16 MFMA causal flash attention — swapped QK^T + permuted K rows
// (P stays in registers), causal pair-balancing, K/V LDS double-buffer,
// cvt_pk P-pack (T12), defer-max THR=8 (T13), no setprio (T5 regime
// mismatch measured r11). Identical to round 12 (126.5 us measured).
// ---------------------------------------------------------------------------
template <bool SPLITOUT>
__global__ __launch_bounds__(256, 2) void attn_mfma_kernel(
    const ushort* __restrict__ Qh, const ushort* __restrict__ Ql,
    const ushort* __restrict__ Kh, const ushort* __restrict__ Kl,
    const ushort* __restrict__ Vth, const ushort* __restrict__ Vtl,
    float* __restrict__ O, ushort* __restrict__ Oh, ushort* __restrict__ Ol) {
  __shared__ __align__(16) ushort KHs[2][64 * 64], KLs[2][64 * 64];
  __shared__ __align__(16) ushort VHs[2][64 * 64], VLs[2][64 * 64];  // 64 KB

  const int bh = blockIdx.x;
  const int qtA = blockIdx.y;  // 0..7, paired with qtB = 15 - qtA
  const int qtB = 15 - qtA;
  const int t = threadIdx.x;
  const int lane = t & 63, wave = t >> 6;
  const int fr = lane & 15, kg = lane >> 4;
  const int base = bh * (SEQ * HD);  // same for [bh,s,d] and [bh,d,s]
  const int r8 = lane >> 3, c8 = lane & 7;

  const int q00[2] = {qtA * 128 + wave * 32, qtB * 128 + wave * 32};
  const int ext[2] = {(q00[0] + 95) >> 6, (q00[1] + 95) >> 6};
  const int nkt = 2 * qtB + 2;  // block-level tile count (= max ext)

  // ---- Q fragments for both q-groups (already scaled + split) ----
  short8 qfh[2][2][2], qfl[2][2][2];  // [grp][mf][ks]
#pragma unroll
  for (int g = 0; g < 2; ++g)
#pragma unroll
    for (int mf = 0; mf < 2; ++mf)
#pragma unroll
      for (int ks = 0; ks < 2; ++ks) {
        const int idx = base + (q00[g] + mf * 16 + fr) * HD + ks * 32 + kg * 8;
        qfh[g][mf][ks] = *(const short8*)&Qh[idx];
        qfl[g][mf][ks] = *(const short8*)&Ql[idx];
      }

  floatx4 oacc[2][2][4];  // [grp][mf][nf]
  float m_run[2][2], l_run[2][2];
#pragma unroll
  for (int g = 0; g < 2; ++g)
#pragma unroll
    for (int mf = 0; mf < 2; ++mf) {
#pragma unroll
      for (int nf = 0; nf < 4; ++nf)
#pragma unroll
        for (int r = 0; r < 4; ++r) oacc[g][mf][nf][r] = 0.f;
      m_run[g][mf] = -INFINITY;
      l_run[g][mf] = 0.f;
    }

  // stage tile kt into buffer b (8 gll per wave; src-swizzled, linear dest)
  auto stage = [&](int kt, int b) {
#pragma unroll
    for (int i = 0; i < 2; ++i) {
      const int lrow = wave * 16 + i * 8;
      const int row = lrow + r8;               // kv-row / d-row, 0..63
      const int sw = (c8 ^ (row & 7)) << 3;    // swizzled bf16 offset in row
      const int gk = base + (kt * 64 + row) * HD + sw;
      const int gv = base + row * SEQ + kt * 64 + sw;
      load16(Kh + gk, (char*)KHs + b * 8192 + lrow * 128);
      load16(Kl + gk, (char*)KLs + b * 8192 + lrow * 128);
      load16(Vth + gv, (char*)VHs + b * 8192 + lrow * 128);
      load16(Vtl + gv, (char*)VLs + b * 8192 + lrow * 128);
    }
  };

  stage(0, 0);
  asm volatile("s_waitcnt vmcnt(0)");
  __syncthreads();

#pragma unroll 1
  for (int kt = 0; kt < nkt; ++kt) {
    const int cur = kt & 1;
    if (kt + 1 < nkt) stage(kt + 1, cur ^ 1);  // prefetch overlaps compute
    const int c0 = kt * 64;
    const int kb = cur * 8192;  // byte offset of current buffer

#pragma unroll
    for (int g = 0; g < 2; ++g) {
      if (kt < ext[g]) {
        const int q0 = q00[g];

        // ---- S^T = K_perm Q (split-bf16, 3 MFMA) ----
        floatx4 s2[2][4];
#pragma unroll
        for (int mf = 0; mf < 2; ++mf)
#pragma unroll
          for (int nf = 0; nf < 4; ++nf)
#pragma unroll
            for (int r = 0; r < 4; ++r) s2[mf][nf][r] = 0.f;

#pragma unroll
        for (int ksd = 0; ksd < 2; ++ksd)
#pragma unroll
          for (int nf = 0; nf < 4; ++nf) {
            const int kr =
                32 * (nf >> 1) + 8 * (fr >> 2) + 4 * (nf & 1) + (fr & 3);
            const int byo = kb + kr * 128 + (((ksd * 4 + kg) ^ (kr & 7)) << 4);
            const short8 kh = *(const short8*)((const char*)KHs + byo);
            const short8 kl = *(const short8*)((const char*)KLs + byo);
#pragma unroll
            for (int mf = 0; mf < 2; ++mf) {
              s2[mf][nf] = __builtin_amdgcn_mfma_f32_16x16x32_bf16(
                  kh, qfh[g][mf][ksd], s2[mf][nf], 0, 0, 0);
              s2[mf][nf] = __builtin_amdgcn_mfma_f32_16x16x32_bf16(
                  kh, qfl[g][mf][ksd], s2[mf][nf], 0, 0, 0);
              s2[mf][nf] = __builtin_amdgcn_mfma_f32_16x16x32_bf16(
                  kl, qfh[g][mf][ksd], s2[mf][nf], 0, 0, 0);
            }
          }

        // ---- causal mask (edge tiles only); col from permuted mapping ----
        if (c0 + 63 > q0) {
#pragma unroll
          for (int mf = 0; mf < 2; ++mf)
#pragma unroll
            for (int nf = 0; nf < 4; ++nf)
#pragma unroll
              for (int r = 0; r < 4; ++r) {
                const int col =
                    c0 + 32 * (nf >> 1) + 8 * kg + 4 * (nf & 1) + r;
                const int row = q0 + mf * 16 + fr;
                if (col > row) s2[mf][nf][r] = -1e9f;
              }
        }

        // ---- online softmax with defer-max (THR=8, wave-uniform vote) ----
        float pmv[2];
#pragma unroll
        for (int mf = 0; mf < 2; ++mf) {
          float pm = s2[mf][0][0];
#pragma unroll
          for (int nf = 0; nf < 4; ++nf)
#pragma unroll
            for (int r = 0; r < 4; ++r) pm = fmaxf(pm, s2[mf][nf][r]);
          pm = fmaxf(pm, __shfl_xor(pm, 16));
          pm = fmaxf(pm, __shfl_xor(pm, 32));
          pmv[mf] = pm;
        }
        float alpha2[2] = {1.f, 1.f};
        const bool grow = !__all((pmv[0] <= m_run[g][0] + 8.f) &&
                                 (pmv[1] <= m_run[g][1] + 8.f));
        if (grow) {
#pragma unroll
          for (int mf = 0; mf < 2; ++mf) {
            const float mnew = fmaxf(m_run[g][mf], pmv[mf]);
            alpha2[mf] = __expf(m_run[g][mf] - mnew);
            m_run[g][mf] = mnew;
          }
          // rescale oacc (alpha redistributed to C/D row owners)
#pragma unroll
          for (int mf = 0; mf < 2; ++mf)
#pragma unroll
            for (int r = 0; r < 4; ++r) {
              const float a = __shfl(alpha2[mf], (kg * 4 + r) | (lane & 48));
#pragma unroll
              for (int nf = 0; nf < 4; ++nf) oacc[g][mf][nf][r] *= a;
            }
        }
#pragma unroll
        for (int mf = 0; mf < 2; ++mf) {
          const float mm = m_run[g][mf];
          float sum = 0.f;
#pragma unroll
          for (int nf = 0; nf < 4; ++nf)
#pragma unroll
            for (int r = 0; r < 4; ++r) {
              const float p = __expf(s2[mf][nf][r] - mm);
              s2[mf][nf][r] = p;
              sum += p;
            }
          sum += __shfl_xor(sum, 16);
          sum += __shfl_xor(sum, 32);
          l_run[g][mf] = l_run[g][mf] * alpha2[mf] + sum;
        }

        // ---- pack P into PV A-fragments via v_cvt_pk_bf16_f32 (T12) ----
        short8 pah[2][2], pal[2][2];
#pragma unroll
        for (int mf = 0; mf < 2; ++mf)
#pragma unroll
          for (int ks = 0; ks < 2; ++ks) {
            uintx4 H, L;
#pragma unroll
            for (int jj = 0; jj < 4; ++jj) {
              const int nfi = 2 * ks + (jj >> 1);
              uint h, l;
              split_pair(s2[mf][nfi][(2 * jj) & 3], s2[mf][nfi][(2 * jj + 1) & 3],
                         h, l);
              H[jj] = h;
              L[jj] = l;
            }
            pah[mf][ks] = *(short8*)&H;
            pal[mf][ks] = *(short8*)&L;
          }

        // ---- O += P V (split-bf16), V^T frags from swizzled LDS ----
#pragma unroll
        for (int ks = 0; ks < 2; ++ks)
#pragma unroll
          for (int nf = 0; nf < 4; ++nf) {
            const int d = nf * 16 + fr;
            const int byo = kb + d * 128 + (((ks * 4 + kg) ^ (d & 7)) << 4);
            const short8 vh = *(const short8*)((const char*)VHs + byo);
            const short8 vl = *(const short8*)((const char*)VLs + byo);
#pragma unroll
            for (int mf = 0; mf < 2; ++mf) {
              oacc[g][mf][nf] = __builtin_amdgcn_mfma_f32_16x16x32_bf16(
                  pah[mf][ks], vh, oacc[g][mf][nf], 0, 0, 0);
              oacc[g][mf][nf] = __builtin_amdgcn_mfma_f32_16x16x32_bf16(
                  pah[mf][ks], vl, oacc[g][mf][nf], 0, 0, 0);
              oacc[g][mf][nf] = __builtin_amdgcn_mfma_f32_16x16x32_bf16(
                  pal[mf][ks], vh, oacc[g][mf][nf], 0, 0, 0);
            }
          }
      }
    }

    asm volatile("s_waitcnt vmcnt(0)");  // next-tile stage complete
    __syncthreads();
  }

  // ---- epilogue: AO[m = b*SEQ+s][e = h*64+d]; l redistributed like alpha ----
  const int b = bh >> 4, hsel = bh & 15;
#pragma unroll
  for (int g = 0; g < 2; ++g)
#pragma unroll
    for (int mf = 0; mf < 2; ++mf)
#pragma unroll
      for (int r = 0; r < 4; ++r) {
        const float lv = __shfl(l_run[g][mf], (kg * 4 + r) | (lane & 48));
        const float inv = 1.f / lv;
        const int grow2 = q00[g] + mf * 16 + kg * 4 + r;
        const int rowbase = (b * SEQ + grow2) * EMB + hsel * HD;
#pragma unroll
        for (int nf = 0; nf < 4; ++nf) {
          const float val = oacc[g][mf][nf][r] * inv;
          const int idx = rowbase + nf * 16 + fr;
          if constexpr (SPLITOUT) {
            const ushort hh = f2bf_rne(val);
            Oh[idx] = hh;
            Ol[idx] = f2bf_rne(val - bf2f(hh));
          } else {
            O[idx] = val;
          }
        }
      }
}

// ---------------------------------------------------------------------------
extern "C" void kernel_launch(void* const* d_in, const int* in_sizes, int n_in,
                              void* d_out, int out_size, void* d_ws,
                              size_t ws_size, hipStream_t stream) {
  const float* q = (const float*)d_in[0];
  const float* k = (const float*)d_in[1];
  const float* v = (const float*)d_in[2];
  // d_in[3] = causal mask (tril by construction) -> predicate col>row instead
  const float* Wq = (const float*)d_in[4];
  const float* bq = (const float*)d_in[5];
  const float* Wk = (const float*)d_in[6];
  const float* bk = (const float*)d_in[7];
  const float* Wv = (const float*)d_in[8];
  const float* bv = (const float*)d_in[9];
  const float* Wo = (const float*)d_in[10];
  const float* bo = (const float*)d_in[11];
  float* out = (float*)d_out;

  const size_t E = (size_t)BATCH * SEQ * EMB;  // 8388608 elements
  const size_t WE = (size_t)EMB * EMB;         // 1048576 elements
  ushort* us = (ushort*)d_ws;
  ushort* Qh = us;
  ushort* Ql = us + E;
  ushort* Kh = us + 2 * E;
  ushort* Kl = us + 3 * E;
  ushort* Vth = us + 4 * E;
  ushort* Vtl = us + 5 * E;

  const dim3 pgrid(EMB / 128, (BATCH * SEQ) / 128);  // (8, 64)
  const dim3 agrid(BATCH * NH, 8);                   // paired q-tiles
  const dim3 blk(256);
  const int wgrid = (int)(WE / 8 / 256);  // 512 blocks per weight matrix

  if (ws_size >= 8 * E * sizeof(ushort)) {
    // ---- Tier A (ws >= 134.2 MB) ----
    ushort* W3 = us + 6 * E;
    ushort* Wqh = W3, *Wql = W3 + WE;
    ushort* Wkh = W3 + 2 * WE, *Wkl = W3 + 3 * WE;
    ushort* Wvh = W3 + 4 * WE, *Wvl = W3 + 5 * WE;
    ushort* AOh = us + 6 * E, *AOl = us + 7 * E;  // overwrites W3 post-projs
    ushort* Woh = us, *Wol = us + WE;             // Qh region, dead post-attn

    wconv3_kernel<<<3 * wgrid, blk, 0, stream>>>(Wq, Wk, Wv, Wqh, Wql, Wkh,
                                                 Wkl, Wvh, Wvl);
    proj_mfma_kernel<0, false, true><<<pgrid, blk, 0, stream>>>(
        q, nullptr, nullptr, nullptr, Wqh, Wql, bq, nullptr, Qh, Ql);
    proj_mfma_kernel<1, false, true><<<pgrid, blk, 0, stream>>>(
        k, nullptr, nullptr, nullptr, Wkh, Wkl, bk, nullptr, Kh, Kl);
    proj_mfma_kernel<2, false, true><<<pgrid, blk, 0, stream>>>(
        v, nullptr, nullptr, nullptr, Wvh, Wvl, bv, nullptr, Vth, Vtl);
    attn_mfma_kernel<true><<<agrid, blk, 0, stream>>>(Qh, Ql, Kh, Kl, Vth, Vtl,
                                                      nullptr, AOh, AOl);
    wconv_kernel<<<wgrid, blk, 0, stream>>>(Wo, Woh, Wol);
    proj_mfma_kernel<3, true, true><<<pgrid, blk, 0, stream>>>(
        nullptr, AOh, AOl, nullptr, Woh, Wol, bo, out, nullptr, nullptr);
  } else if (ws_size >= (6 * E + 6 * WE) * sizeof(ushort)) {
    // ---- Tier B (ws >= 113.3 MB): AO hi/lo lives in `out` ----
    ushort* W3 = us + 6 * E;
    ushort* Wqh = W3, *Wql = W3 + WE;
    ushort* Wkh = W3 + 2 * WE, *Wkl = W3 + 3 * WE;
    ushort* Wvh = W3 + 4 * WE, *Wvl = W3 + 5 * WE;
    ushort* AOh = (ushort*)d_out, *AOl = AOh + E;
    ushort* Woh = us, *Wol = us + WE;
    float* PO = (float*)(us + 2 * E);

    wconv3_kernel<<<3 * wgrid, blk, 0, stream>>>(Wq, Wk, Wv, Wqh, Wql, Wkh,
                                                 Wkl, Wvh, Wvl);
    proj_mfma_kernel<0, false, true><<<pgrid, blk, 0, stream>>>(
        q, nullptr, nullptr, nullptr, Wqh, Wql, bq, nullptr, Qh, Ql);
    proj_mfma_kernel<1, false, true><<<pgrid, blk, 0, stream>>>(
        k, nullptr, nullptr, nullptr, Wkh, Wkl, bk, nullptr, Kh, Kl);
    proj_mfma_kernel<2, false, true><<<pgrid, blk, 0, stream>>>(
        v, nullptr, nullptr, nullptr, Wvh, Wvl, bv, nullptr, Vth, Vtl);
    attn_mfma_kernel<true><<<agrid, blk, 0, stream>>>(Qh, Ql, Kh, Kl, Vth, Vtl,
                                                      nullptr, AOh, AOl);
    wconv_kernel<<<wgrid, blk, 0, stream>>>(Wo, Woh, Wol);
    proj_mfma_kernel<3, true, true><<<pgrid, blk, 0, stream>>>(
        nullptr, AOh, AOl, nullptr, Woh, Wol, bo, PO, nullptr, nullptr);
    hipError_t e1 = hipMemcpyAsync(out, PO, E * sizeof(float),
                                   hipMemcpyDeviceToDevice, stream);
    (void)e1;
  } else {
    // ---- Tier C: in-kernel W conversion, fp32 AO (single-buffer legacy) ----
    float* AO = out;
    float* PO = (float*)d_ws;
    proj_mfma_kernel<0, false, false><<<pgrid, blk, 0, stream>>>(
        q, nullptr, nullptr, Wq, nullptr, nullptr, bq, nullptr, Qh, Ql);
    proj_mfma_kernel<1, false, false><<<pgrid, blk, 0, stream>>>(
        k, nullptr, nullptr, Wk, nullptr, nullptr, bk, nullptr, Kh, Kl);
    proj_mfma_kernel<2, false, false><<<pgrid, blk, 0, stream>>>(
        v, nullptr, nullptr, Wv, nullptr, nullptr, bv, nullptr, Vth, Vtl);
    attn_mfma_kernel<false><<<agrid, blk, 0, stream>>>(
        Qh, Ql, Kh, Kl, Vth, Vtl, AO, nullptr, nullptr);
    proj_mfma_kernel<3, false, false><<<pgrid, blk, 0, stream>>>(
        AO, nullptr, nullptr, Wo, nullptr, nullptr, bo, PO, nullptr, nullptr);
    hipError_t e2 = hipMemcpyAsync(out, PO, E * sizeof(float),
                                   hipMemcpyDeviceToDevice, stream);
    (void)e2;
  }
}

// Round 14
// 361.161 us; speedup vs baseline: 1.0906x; 1.0155x over previous
//
#include <hip/hip_runtime.h>

#define SEQ   2048
#define EMB   1024
#define NH    16
#define HD    64
#define BATCH 4

typedef __attribute__((ext_vector_type(8))) short short8;   // 8 bf16 = 4 VGPR
typedef __attribute__((ext_vector_type(4))) float floatx4;  // MFMA acc
typedef __attribute__((ext_vector_type(4))) uint uintx4;

// bf16 round-to-nearest-even (integer trick; bit-identical to v_cvt_pk RNE).
static __device__ __forceinline__ ushort f2bf_rne(float x) {
  unsigned u = __float_as_uint(x);
  unsigned r = u + 0x7FFFu + ((u >> 16) & 1u);
  return (ushort)(r >> 16);
}
static __device__ __forceinline__ float bf2f(ushort h) {
  return __uint_as_float(((unsigned)h) << 16);
}

// HW packed f32->bf16 RNE: dst = bf16(a) | bf16(b)<<16  (1 VALU op).
static __device__ __forceinline__ uint pk_bf16(float a, float b) {
  uint r;
  asm("v_cvt_pk_bf16_f32 %0, %1, %2" : "=v"(r) : "v"(a), "v"(b));
  return r;
}
// Split two floats into packed hi and packed lo words (~6 ops/pair).
static __device__ __forceinline__ void split_pair(float a, float b, uint& h,
                                                  uint& l) {
  h = pk_bf16(a, b);
  const float ha = __uint_as_float(h << 16);
  const float hb = __uint_as_float(h & 0xFFFF0000u);
  l = pk_bf16(a - ha, b - hb);
}

// Async global->LDS, 16 bytes per lane. LDS dest must be wave-uniform base
// (+ lane*16 implicit); global src is per-lane.
static __device__ __forceinline__ void load16(const void* g, void* l) {
  __builtin_amdgcn_global_load_lds(
      (const __attribute__((address_space(1))) unsigned int*)g,
      (__attribute__((address_space(3))) unsigned int*)l, 16, 0, 0);
}

// Swizzled LDS byte offset for a 128x32-ushort tile staged linearly.
static __device__ __forceinline__ int swz_off(int row, int kg) {
  return (row >> 1) * 128 + (((row & 1) << 2) + (kg ^ ((row >> 1) & 3))) * 16;
}

// Stage one 128x32-ushort tile (8 KB) from pre-split global [ld=EMB] via
// global_load_lds: per-lane INVERSE-swizzled source, linear LDS dest.
static __device__ __forceinline__ void stage_tile(const ushort* __restrict__ g,
                                                  int row0, int k0,
                                                  ushort* lds, int t) {
#pragma unroll
  for (int i = 0; i < 2; ++i) {
    const int slot = t + i * 256;            // 0..511
    const int line = slot >> 3, s = slot & 7;
    const int row = line * 2 + (s >> 2);
    const int c = (s & 3) ^ (line & 3);
    load16(g + (size_t)(row0 + row) * EMB + k0 + c * 8, lds + slot * 8);
  }
}

// ---------------------------------------------------------------------------
// fp32 -> hi/lo bf16 split converters for weight matrices.
// wconv4: all four W matrices in ONE launch (512 blocks each).
// wconv3/wconv: fallbacks for smaller-ws tiers.
// ---------------------------------------------------------------------------
static __device__ __forceinline__ void wconv_body(const float* W, ushort* Yh,
                                                  ushort* Yl, int bid, int t) {
  const int i = (bid * 256 + t) * 8;
  const float4 a = *(const float4*)(W + i);
  const float4 b = *(const float4*)(W + i + 4);
  const float xv[8] = {a.x, a.y, a.z, a.w, b.x, b.y, b.z, b.w};
  uintx4 H, L;
#pragma unroll
  for (int j = 0; j < 4; ++j) {
    uint h, l;
    split_pair(xv[2 * j], xv[2 * j + 1], h, l);
    H[j] = h;
    L[j] = l;
  }
  *(uintx4*)&Yh[i] = H;
  *(uintx4*)&Yl[i] = L;
}

__global__ __launch_bounds__(256) void wconv4_kernel(
    const float* __restrict__ Wq, const float* __restrict__ Wk,
    const float* __restrict__ Wv, const float* __restrict__ Wo,
    ushort* __restrict__ Yqh, ushort* __restrict__ Yql,
    ushort* __restrict__ Ykh, ushort* __restrict__ Ykl,
    ushort* __restrict__ Yvh, ushort* __restrict__ Yvl,
    ushort* __restrict__ Yoh, ushort* __restrict__ Yol) {
  const int which = blockIdx.x >> 9;
  const int bid = blockIdx.x & 511;
  const float* W = which == 0 ? Wq : which == 1 ? Wk : which == 2 ? Wv : Wo;
  ushort* Yh = which == 0 ? Yqh : which == 1 ? Ykh : which == 2 ? Yvh : Yoh;
  ushort* Yl = which == 0 ? Yql : which == 1 ? Ykl : which == 2 ? Yvl : Yol;
  wconv_body(W, Yh, Yl, bid, threadIdx.x);
}

__global__ __launch_bounds__(256) void wconv3_kernel(
    const float* __restrict__ Wq, const float* __restrict__ Wk,
    const float* __restrict__ Wv, ushort* __restrict__ Yqh,
    ushort* __restrict__ Yql, ushort* __restrict__ Ykh,
    ushort* __restrict__ Ykl, ushort* __restrict__ Yvh,
    ushort* __restrict__ Yvl) {
  const int which = blockIdx.x >> 9;
  const int bid = blockIdx.x & 511;
  const float* W = which == 0 ? Wq : which == 1 ? Wk : Wv;
  ushort* Yh = which == 0 ? Yqh : which == 1 ? Ykh : Yvh;
  ushort* Yl = which == 0 ? Yql : which == 1 ? Ykl : Yvl;
  wconv_body(W, Yh, Yl, bid, threadIdx.x);
}

__global__ __launch_bounds__(256) void wconv_kernel(const float* __restrict__ W,
                                                    ushort* __restrict__ Yh,
                                                    ushort* __restrict__ Yl) {
  wconv_body(W, Yh, Yl, blockIdx.x, threadIdx.x);
}

// ---------------------------------------------------------------------------
// FUSED QKV projection: one launch, grid (8, 64, 3); z selects {Q,K,V}.
// Body identical to r13's PREB(!PREA) proj: B via async gload_lds dbuf,
// A (fp32 X) converted+ds_written to buf^1 before computing buf cur.
// Epilogue mode: 0 = Q (*0.125, [bh,s,d]); 1 = K; 2 = V transposed [bh,d,s].
// ---------------------------------------------------------------------------
__global__ __launch_bounds__(256) void qkv_proj_kernel(
    const float* __restrict__ Xq, const float* __restrict__ Xk,
    const float* __restrict__ Xv, const ushort* __restrict__ Wqh,
    const ushort* __restrict__ Wql, const ushort* __restrict__ Wkh,
    const ushort* __restrict__ Wkl, const ushort* __restrict__ Wvh,
    const ushort* __restrict__ Wvl, const float* __restrict__ bq,
    const float* __restrict__ bk, const float* __restrict__ bv,
    ushort* __restrict__ Qh, ushort* __restrict__ Ql, ushort* __restrict__ Kh,
    ushort* __restrict__ Kl, ushort* __restrict__ Vth,
    ushort* __restrict__ Vtl) {
  __shared__ ushort Ahi[2][128 * 40], Alo[2][128 * 40];
  __shared__ ushort Bhi[2][128 * 32], Blo[2][128 * 32];

  const int mode = blockIdx.z;
  const float* X = mode == 0 ? Xq : mode == 1 ? Xk : Xv;
  const ushort* Wh = mode == 0 ? Wqh : mode == 1 ? Wkh : Wvh;
  const ushort* Wl = mode == 0 ? Wql : mode == 1 ? Wkl : Wvl;
  const float* bias = mode == 0 ? bq : mode == 1 ? bk : bv;
  ushort* Yh = mode == 0 ? Qh : mode == 1 ? Kh : Vth;
  ushort* Yl = mode == 0 ? Ql : mode == 1 ? Kl : Vtl;

  const int t = threadIdx.x;
  const int lane = t & 63, wave = t >> 6;
  const int m0 = blockIdx.y * 128, n0 = blockIdx.x * 128;
  const int wm = (wave >> 1) * 64, wn = (wave & 1) * 64;
  const int fr = lane & 15, kg = lane >> 4;

  floatx4 acc[4][4];
#pragma unroll
  for (int i = 0; i < 4; ++i)
#pragma unroll
    for (int j = 0; j < 4; ++j)
#pragma unroll
      for (int r = 0; r < 4; ++r) acc[i][j][r] = 0.f;

  auto stageB = [&](int k0, int b) {
    stage_tile(Wh, n0, k0, Bhi[b], t);
    stage_tile(Wl, n0, k0, Blo[b], t);
  };
  auto stageA = [&](int k0, int b) {
#pragma unroll
    for (int i = 0; i < 4; ++i) {
      const int f = t + 256 * i;
      const int row = f >> 3, kq = f & 7;
      const float4 v =
          *(const float4*)(X + (size_t)(m0 + row) * EMB + k0 + kq * 4);
      uint h0, l0, h1, l1;
      split_pair(v.x, v.y, h0, l0);
      split_pair(v.z, v.w, h1, l1);
      uint2 hp, lp;
      hp.x = h0; hp.y = h1;
      lp.x = l0; lp.y = l1;
      *(uint2*)&Ahi[b][row * 40 + kq * 4] = hp;
      *(uint2*)&Alo[b][row * 40 + kq * 4] = lp;
    }
  };
  auto computeStep = [&](int cur) {
    short8 bhv[4], blv[4];
#pragma unroll
    for (int nf = 0; nf < 4; ++nf) {
      const int row = wn + nf * 16 + fr;
      const int off = swz_off(row, kg);
      bhv[nf] = *(const short8*)((const char*)Bhi[cur] + off);
      blv[nf] = *(const short8*)((const char*)Blo[cur] + off);
    }
#pragma unroll
    for (int mf = 0; mf < 4; ++mf) {
      const int arow = wm + mf * 16 + fr;
      const short8 ah = *(const short8*)&Ahi[cur][arow * 40 + kg * 8];
      const short8 al = *(const short8*)&Alo[cur][arow * 40 + kg * 8];
#pragma unroll
      for (int nf = 0; nf < 4; ++nf) {
        acc[mf][nf] = __builtin_amdgcn_mfma_f32_16x16x32_bf16(ah, bhv[nf],
                                                              acc[mf][nf], 0, 0, 0);
        acc[mf][nf] = __builtin_amdgcn_mfma_f32_16x16x32_bf16(ah, blv[nf],
                                                              acc[mf][nf], 0, 0, 0);
        acc[mf][nf] = __builtin_amdgcn_mfma_f32_16x16x32_bf16(al, bhv[nf],
                                                              acc[mf][nf], 0, 0, 0);
      }
    }
  };

  stageB(0, 0);
  stageA(0, 0);
  asm volatile("s_waitcnt vmcnt(0)");
  __syncthreads();
#pragma unroll 1
  for (int k0 = 0; k0 < EMB; k0 += 32) {
    const int cur = (k0 >> 5) & 1;
    if (k0 + 32 < EMB) {  // prefetch next tile; loads overlap compute
      stageB(k0 + 32, cur ^ 1);
      stageA(k0 + 32, cur ^ 1);
    }
    computeStep(cur);
    asm volatile("s_waitcnt vmcnt(0)");
    __syncthreads();
  }

  // ---- epilogue: C/D layout col = lane&15, row = (lane>>4)*4 + reg ----
  const int rg = lane >> 4;
#pragma unroll
  for (int nf = 0; nf < 4; ++nf) {
    const int n = n0 + wn + nf * 16 + fr;
    const float bb = bias[n];
    if (mode == 2) {
      const int hh = n >> 6, d = n & 63;
#pragma unroll
      for (int mf = 0; mf < 4; ++mf) {
        const int mb = m0 + wm + mf * 16 + rg * 4;
        const int b = mb >> 11, s = mb & (SEQ - 1);
        uint h0, l0, h1, l1;
        split_pair(acc[mf][nf][0] + bb, acc[mf][nf][1] + bb, h0, l0);
        split_pair(acc[mf][nf][2] + bb, acc[mf][nf][3] + bb, h1, l1);
        uint2 hp, lp;
        hp.x = h0; hp.y = h1;
        lp.x = l0; lp.y = l1;
        const int idx = (b * NH + hh) * (HD * SEQ) + d * SEQ + s;
        *(uint2*)&Yh[idx] = hp;
        *(uint2*)&Yl[idx] = lp;
      }
    } else {
      const float scaleq = (mode == 0) ? 0.125f : 1.0f;
#pragma unroll
      for (int mf = 0; mf < 4; ++mf) {
#pragma unroll
        for (int r = 0; r < 4; ++r) {
          const int m = m0 + wm + mf * 16 + rg * 4 + r;
          const float val = (acc[mf][nf][r] + bb) * scaleq;
          const int hh = n >> 6, d = n & 63;
          const int b = m >> 11, s = m & (SEQ - 1);
          const int idx = ((b * NH + hh) * SEQ + s) * HD + d;
          const ushort h = f2bf_rne(val);
          Yh[idx] = h;
          Yl[idx] = f2bf_rne(val - bf2f(h));
        }
      }
    }
  }
}

// ---------------------------------------------------------------------------
// Templated projection (O-proj PREA+PREB; Tier-C fp32 fallbacks).
// ---------------------------------------------------------------------------
template <int MODE, bool PREA, bool PREB>
__global__ __launch_bounds__(256) void proj_mfma_kernel(
    const float* __restrict__ X, const ushort* __restrict__ Xh,
    const ushort* __restrict__ Xl, const float* __restrict__ W,
    const ushort* __restrict__ Wh, const ushort* __restrict__ Wl,
    const float* __restrict__ bias, float* __restrict__ Yf,
    ushort* __restrict__ Yh, ushort* __restrict__ Yl) {
  constexpr bool DBUF = (PREA || PREB);
  constexpr int NB = DBUF ? 2 : 1;
  constexpr int ASZ = PREA ? 128 * 32 : 128 * 40;
  constexpr int BSZ = PREB ? 128 * 32 : 128 * 40;
  __shared__ ushort Ahi[NB][ASZ], Alo[NB][ASZ];
  __shared__ ushort Bhi[NB][BSZ], Blo[NB][BSZ];

  const int t = threadIdx.x;
  const int lane = t & 63, wave = t >> 6;
  const int m0 = blockIdx.y * 128, n0 = blockIdx.x * 128;
  const int wm = (wave >> 1) * 64, wn = (wave & 1) * 64;
  const int fr = lane & 15, kg = lane >> 4;

  floatx4 acc[4][4];
#pragma unroll
  for (int i = 0; i < 4; ++i)
#pragma unroll
    for (int j = 0; j < 4; ++j)
#pragma unroll
      for (int r = 0; r < 4; ++r) acc[i][j][r] = 0.f;

  auto stageB = [&](int k0, int b) {
    if constexpr (PREB) {
      stage_tile(Wh, n0, k0, Bhi[b], t);
      stage_tile(Wl, n0, k0, Blo[b], t);
    } else {
#pragma unroll
      for (int i = 0; i < 4; ++i) {
        const int f = t + 256 * i;
        const int row = f >> 3, kq = f & 7;
        const float4 v =
            *(const float4*)(W + (size_t)(n0 + row) * EMB + k0 + kq * 4);
        uint h0, l0, h1, l1;
        split_pair(v.x, v.y, h0, l0);
        split_pair(v.z, v.w, h1, l1);
        uint2 hp, lp;
        hp.x = h0; hp.y = h1;
        lp.x = l0; lp.y = l1;
        *(uint2*)&Bhi[b][row * 40 + kq * 4] = hp;
        *(uint2*)&Blo[b][row * 40 + kq * 4] = lp;
      }
    }
  };
  auto stageA = [&](int k0, int b) {
    if constexpr (PREA) {
      stage_tile(Xh, m0, k0, Ahi[b], t);
      stage_tile(Xl, m0, k0, Alo[b], t);
    } else {
#pragma unroll
      for (int i = 0; i < 4; ++i) {
        const int f = t + 256 * i;
        const int row = f >> 3, kq = f & 7;
        const float4 v =
            *(const float4*)(X + (size_t)(m0 + row) * EMB + k0 + kq * 4);
        uint h0, l0, h1, l1;
        split_pair(v.x, v.y, h0, l0);
        split_pair(v.z, v.w, h1, l1);
        uint2 hp, lp;
        hp.x = h0; hp.y = h1;
        lp.x = l0; lp.y = l1;
        *(uint2*)&Ahi[b][row * 40 + kq * 4] = hp;
        *(uint2*)&Alo[b][row * 40 + kq * 4] = lp;
      }
    }
  };
  auto computeStep = [&](int cur) {
    short8 bhv[4], blv[4];
#pragma unroll
    for (int nf = 0; nf < 4; ++nf) {
      const int row = wn + nf * 16 + fr;
      if constexpr (PREB) {
        const int off = swz_off(row, kg);
        bhv[nf] = *(const short8*)((const char*)Bhi[cur] + off);
        blv[nf] = *(const short8*)((const char*)Blo[cur] + off);
      } else {
        bhv[nf] = *(const short8*)&Bhi[cur][row * 40 + kg * 8];
        blv[nf] = *(const short8*)&Blo[cur][row * 40 + kg * 8];
      }
    }
#pragma unroll
    for (int mf = 0; mf < 4; ++mf) {
      const int arow = wm + mf * 16 + fr;
      short8 ah, al;
      if constexpr (PREA) {
        const int off = swz_off(arow, kg);
        ah = *(const short8*)((const char*)Ahi[cur] + off);
        al = *(const short8*)((const char*)Alo[cur] + off);
      } else {
        ah = *(const short8*)&Ahi[cur][arow * 40 + kg * 8];
        al = *(const short8*)&Alo[cur][arow * 40 + kg * 8];
      }
#pragma unroll
      for (int nf = 0; nf < 4; ++nf) {
        acc[mf][nf] = __builtin_amdgcn_mfma_f32_16x16x32_bf16(ah, bhv[nf],
                                                              acc[mf][nf], 0, 0, 0);
        acc[mf][nf] = __builtin_amdgcn_mfma_f32_16x16x32_bf16(ah, blv[nf],
                                                              acc[mf][nf], 0, 0, 0);
        acc[mf][nf] = __builtin_amdgcn_mfma_f32_16x16x32_bf16(al, bhv[nf],
                                                              acc[mf][nf], 0, 0, 0);
      }
    }
  };

  if constexpr (DBUF) {
    stageB(0, 0);
    stageA(0, 0);
    asm volatile("s_waitcnt vmcnt(0)");
    __syncthreads();
#pragma unroll 1
    for (int k0 = 0; k0 < EMB; k0 += 32) {
      const int cur = (k0 >> 5) & 1;
      if (k0 + 32 < EMB) {
        stageB(k0 + 32, cur ^ 1);
        stageA(k0 + 32, cur ^ 1);
      }
      computeStep(cur);
      asm volatile("s_waitcnt vmcnt(0)");
      __syncthreads();
    }
  } else {
#pragma unroll 1
    for (int k0 = 0; k0 < EMB; k0 += 32) {
      __syncthreads();
      stageB(k0, 0);
      stageA(k0, 0);
      __syncthreads();
      computeStep(0);
    }
  }

  // ---- epilogue ----
  const int rg = lane >> 4;
#pragma unroll
  for (int nf = 0; nf < 4; ++nf) {
    const int n = n0 + wn + nf * 16 + fr;
    const float bb = bias[n];
    if (MODE == 2) {
      const int hh = n >> 6, d = n & 63;
#pragma unroll
      for (int mf = 0; mf < 4; ++mf) {
        const int mb = m0 + wm + mf * 16 + rg * 4;
        const int b = mb >> 11, s = mb & (SEQ - 1);
        uint h0, l0, h1, l1;
        split_pair(acc[mf][nf][0] + bb, acc[mf][nf][1] + bb, h0, l0);
        split_pair(acc[mf][nf][2] + bb, acc[mf][nf][3] + bb, h1, l1);
        uint2 hp, lp;
        hp.x = h0; hp.y = h1;
        lp.x = l0; lp.y = l1;
        const int idx = (b * NH + hh) * (HD * SEQ) + d * SEQ + s;
        *(uint2*)&Yh[idx] = hp;
        *(uint2*)&Yl[idx] = lp;
      }
    } else {
#pragma unroll
      for (int mf = 0; mf < 4; ++mf) {
#pragma unroll
        for (int r = 0; r < 4; ++r) {
          const int m = m0 + wm + mf * 16 + rg * 4 + r;
          float val = acc[mf][nf][r] + bb;
          if (MODE == 3) {
            Yf[(size_t)m * EMB + n] = val;
          } else {
            if (MODE == 0) val *= 0.125f;
            const int hh = n >> 6, d = n & 63;
            const int b = m >> 11, s = m & (SEQ - 1);
            const int idx = ((b * NH + hh) * SEQ + s) * HD + d;
            const ushort h = f2bf_rne(val);
            Yh[idx] = h;
            Yl[idx] = f2bf_rne(val - bf2f(h));
          }
        }
      }
    }
  }
}

// ---------------------------------------------------------------------------
// Split-bf16 MFMA causal flash attention — byte-identical to r13 (126.5 us):
// swapped QK^T + permuted K rows (P in registers), causal pair-balancing,
// K/V LDS double-buffer, cvt_pk P-pack (T12), defer-max THR=8 (T13).
// ---------------------------------------------------------------------------
template <bool SPLITOUT>
__global__ __launch_bounds__(256, 2) void attn_mfma_kernel(
    const ushort* __restrict__ Qh, const ushort* __restrict__ Ql,
    const ushort* __restrict__ Kh, const ushort* __restrict__ Kl,
    const ushort* __restrict__ Vth, const ushort* __restrict__ Vtl,
    float* __restrict__ O, ushort* __restrict__ Oh, ushort* __restrict__ Ol) {
  __shared__ __align__(16) ushort KHs[2][64 * 64], KLs[2][64 * 64];
  __shared__ __align__(16) ushort VHs[2][64 * 64], VLs[2][64 * 64];  // 64 KB

  const int bh = blockIdx.x;
  const int qtA = blockIdx.y;  // 0..7, paired with qtB = 15 - qtA
  const int qtB = 15 - qtA;
  const int t = threadIdx.x;
  const int lane = t & 63, wave = t >> 6;
  const int fr = lane & 15, kg = lane >> 4;
  const int base = bh * (SEQ * HD);
  const int r8 = lane >> 3, c8 = lane & 7;

  const int q00[2] = {qtA * 128 + wave * 32, qtB * 128 + wave * 32};
  const int ext[2] = {(q00[0] + 95) >> 6, (q00[1] + 95) >> 6};
  const int nkt = 2 * qtB + 2;

  short8 qfh[2][2][2], qfl[2][2][2];  // [grp][mf][ks]
#pragma unroll
  for (int g = 0; g < 2; ++g)
#pragma unroll
    for (int mf = 0; mf < 2; ++mf)
#pragma unroll
      for (int ks = 0; ks < 2; ++ks) {
        const int idx = base + (q00[g] + mf * 16 + fr) * HD + ks * 32 + kg * 8;
        qfh[g][mf][ks] = *(const short8*)&Qh[idx];
        qfl[g][mf][ks] = *(const short8*)&Ql[idx];
      }

  floatx4 oacc[2][2][4];
  float m_run[2][2], l_run[2][2];
#pragma unroll
  for (int g = 0; g < 2; ++g)
#pragma unroll
    for (int mf = 0; mf < 2; ++mf) {
#pragma unroll
      for (int nf = 0; nf < 4; ++nf)
#pragma unroll
        for (int r = 0; r < 4; ++r) oacc[g][mf][nf][r] = 0.f;
      m_run[g][mf] = -INFINITY;
      l_run[g][mf] = 0.f;
    }

  auto stage = [&](int kt, int b) {
#pragma unroll
    for (int i = 0; i < 2; ++i) {
      const int lrow = wave * 16 + i * 8;
      const int row = lrow + r8;
      const int sw = (c8 ^ (row & 7)) << 3;
      const int gk = base + (kt * 64 + row) * HD + sw;
      const int gv = base + row * SEQ + kt * 64 + sw;
      load16(Kh + gk, (char*)KHs + b * 8192 + lrow * 128);
      load16(Kl + gk, (char*)KLs + b * 8192 + lrow * 128);
      load16(Vth + gv, (char*)VHs + b * 8192 + lrow * 128);
      load16(Vtl + gv, (char*)VLs + b * 8192 + lrow * 128);
    }
  };

  stage(0, 0);
  asm volatile("s_waitcnt vmcnt(0)");
  __syncthreads();

#pragma unroll 1
  for (int kt = 0; kt < nkt; ++kt) {
    const int cur = kt & 1;
    if (kt + 1 < nkt) stage(kt + 1, cur ^ 1);
    const int c0 = kt * 64;
    const int kb = cur * 8192;

#pragma unroll
    for (int g = 0; g < 2; ++g) {
      if (kt < ext[g]) {
        const int q0 = q00[g];

        floatx4 s2[2][4];
#pragma unroll
        for (int mf = 0; mf < 2; ++mf)
#pragma unroll
          for (int nf = 0; nf < 4; ++nf)
#pragma unroll
            for (int r = 0; r < 4; ++r) s2[mf][nf][r] = 0.f;

#pragma unroll
        for (int ksd = 0; ksd < 2; ++ksd)
#pragma unroll
          for (int nf = 0; nf < 4; ++nf) {
            const int kr =
                32 * (nf >> 1) + 8 * (fr >> 2) + 4 * (nf & 1) + (fr & 3);
            const int byo = kb + kr * 128 + (((ksd * 4 + kg) ^ (kr & 7)) << 4);
            const short8 kh = *(const short8*)((const char*)KHs + byo);
            const short8 kl = *(const short8*)((const char*)KLs + byo);
#pragma unroll
            for (int mf = 0; mf < 2; ++mf) {
              s2[mf][nf] = __builtin_amdgcn_mfma_f32_16x16x32_bf16(
                  kh, qfh[g][mf][ksd], s2[mf][nf], 0, 0, 0);
              s2[mf][nf] = __builtin_amdgcn_mfma_f32_16x16x32_bf16(
                  kh, qfl[g][mf][ksd], s2[mf][nf], 0, 0, 0);
              s2[mf][nf] = __builtin_amdgcn_mfma_f32_16x16x32_bf16(
                  kl, qfh[g][mf][ksd], s2[mf][nf], 0, 0, 0);
            }
          }

        if (c0 + 63 > q0) {
#pragma unroll
          for (int mf = 0; mf < 2; ++mf)
#pragma unroll
            for (int nf = 0; nf < 4; ++nf)
#pragma unroll
              for (int r = 0; r < 4; ++r) {
                const int col =
                    c0 + 32 * (nf >> 1) + 8 * kg + 4 * (nf & 1) + r;
                const int row = q0 + mf * 16 + fr;
                if (col > row) s2[mf][nf][r] = -1e9f;
              }
        }

        float pmv[2];
#pragma unroll
        for (int mf = 0; mf < 2; ++mf) {
          float pm = s2[mf][0][0];
#pragma unroll
          for (int nf = 0; nf < 4; ++nf)
#pragma unroll
            for (int r = 0; r < 4; ++r) pm = fmaxf(pm, s2[mf][nf][r]);
          pm = fmaxf(pm, __shfl_xor(pm, 16));
          pm = fmaxf(pm, __shfl_xor(pm, 32));
          pmv[mf] = pm;
        }
        float alpha2[2] = {1.f, 1.f};
        const bool grow = !__all((pmv[0] <= m_run[g][0] + 8.f) &&
                                 (pmv[1] <= m_run[g][1] + 8.f));
        if (grow) {
#pragma unroll
          for (int mf = 0; mf < 2; ++mf) {
            const float mnew = fmaxf(m_run[g][mf], pmv[mf]);
            alpha2[mf] = __expf(m_run[g][mf] - mnew);
            m_run[g][mf] = mnew;
          }
#pragma unroll
          for (int mf = 0; mf < 2; ++mf)
#pragma unroll
            for (int r = 0; r < 4; ++r) {
              const float a = __shfl(alpha2[mf], (kg * 4 + r) | (lane & 48));
#pragma unroll
              for (int nf = 0; nf < 4; ++nf) oacc[g][mf][nf][r] *= a;
            }
        }
#pragma unroll
        for (int mf = 0; mf < 2; ++mf) {
          const float mm = m_run[g][mf];
          float sum = 0.f;
#pragma unroll
          for (int nf = 0; nf < 4; ++nf)
#pragma unroll
            for (int r = 0; r < 4; ++r) {
              const float p = __expf(s2[mf][nf][r] - mm);
              s2[mf][nf][r] = p;
              sum += p;
            }
          sum += __shfl_xor(sum, 16);
          sum += __shfl_xor(sum, 32);
          l_run[g][mf] = l_run[g][mf] * alpha2[mf] + sum;
        }

        short8 pah[2][2], pal[2][2];
#pragma unroll
        for (int mf = 0; mf < 2; ++mf)
#pragma unroll
          for (int ks = 0; ks < 2; ++ks) {
            uintx4 H, L;
#pragma unroll
            for (int jj = 0; jj < 4; ++jj) {
              const int nfi = 2 * ks + (jj >> 1);
              uint h, l;
              split_pair(s2[mf][nfi][(2 * jj) & 3], s2[mf][nfi][(2 * jj + 1) & 3],
                         h, l);
              H[jj] = h;
              L[jj] = l;
            }
            pah[mf][ks] = *(short8*)&H;
            pal[mf][ks] = *(short8*)&L;
          }

#pragma unroll
        for (int ks = 0; ks < 2; ++ks)
#pragma unroll
          for (int nf = 0; nf < 4; ++nf) {
            const int d = nf * 16 + fr;
            const int byo = kb + d * 128 + (((ks * 4 + kg) ^ (d & 7)) << 4);
            const short8 vh = *(const short8*)((const char*)VHs + byo);
            const short8 vl = *(const short8*)((const char*)VLs + byo);
#pragma unroll
            for (int mf = 0; mf < 2; ++mf) {
              oacc[g][mf][nf] = __builtin_amdgcn_mfma_f32_16x16x32_bf16(
                  pah[mf][ks], vh, oacc[g][mf][nf], 0, 0, 0);
              oacc[g][mf][nf] = __builtin_amdgcn_mfma_f32_16x16x32_bf16(
                  pah[mf][ks], vl, oacc[g][mf][nf], 0, 0, 0);
              oacc[g][mf][nf] = __builtin_amdgcn_mfma_f32_16x16x32_bf16(
                  pal[mf][ks], vh, oacc[g][mf][nf], 0, 0, 0);
            }
          }
      }
    }

    asm volatile("s_waitcnt vmcnt(0)");
    __syncthreads();
  }

  const int b = bh >> 4, hsel = bh & 15;
#pragma unroll
  for (int g = 0; g < 2; ++g)
#pragma unroll
    for (int mf = 0; mf < 2; ++mf)
#pragma unroll
      for (int r = 0; r < 4; ++r) {
        const float lv = __shfl(l_run[g][mf], (kg * 4 + r) | (lane & 48));
        const float inv = 1.f / lv;
        const int grow2 = q00[g] + mf * 16 + kg * 4 + r;
        const int rowbase = (b * SEQ + grow2) * EMB + hsel * HD;
#pragma unroll
        for (int nf = 0; nf < 4; ++nf) {
          const float val = oacc[g][mf][nf][r] * inv;
          const int idx = rowbase + nf * 16 + fr;
          if constexpr (SPLITOUT) {
            const ushort hh = f2bf_rne(val);
            Oh[idx] = hh;
            Ol[idx] = f2bf_rne(val - bf2f(hh));
          } else {
            O[idx] = val;
          }
        }
      }
}

// ---------------------------------------------------------------------------
extern "C" void kernel_launch(void* const* d_in, const int* in_sizes, int n_in,
                              void* d_out, int out_size, void* d_ws,
                              size_t ws_size, hipStream_t stream) {
  const float* q = (const float*)d_in[0];
  const float* k = (const float*)d_in[1];
  const float* v = (const float*)d_in[2];
  // d_in[3] = causal mask (tril by construction) -> predicate col>row instead
  const float* Wq = (const float*)d_in[4];
  const float* bq = (const float*)d_in[5];
  const float* Wk = (const float*)d_in[6];
  const float* bk = (const float*)d_in[7];
  const float* Wv = (const float*)d_in[8];
  const float* bv = (const float*)d_in[9];
  const float* Wo = (const float*)d_in[10];
  const float* bo = (const float*)d_in[11];
  float* out = (float*)d_out;

  const size_t E = (size_t)BATCH * SEQ * EMB;  // 8388608 elements
  const size_t WE = (size_t)EMB * EMB;         // 1048576 elements
  ushort* us = (ushort*)d_ws;
  ushort* Qh = us;
  ushort* Ql = us + E;
  ushort* Kh = us + 2 * E;
  ushort* Kl = us + 3 * E;
  ushort* Vth = us + 4 * E;
  ushort* Vtl = us + 5 * E;

  const dim3 pgrid(EMB / 128, (BATCH * SEQ) / 128);  // (8, 64)
  const dim3 qgrid(EMB / 128, (BATCH * SEQ) / 128, 3);
  const dim3 agrid(BATCH * NH, 8);                   // paired q-tiles
  const dim3 blk(256);
  const int wgrid = (int)(WE / 8 / 256);  // 512 blocks per weight matrix

  if (ws_size >= (8 * E + 2 * WE) * sizeof(ushort)) {
    // ---- Tier A2 (ws >= 138.4 MB): all W convs upfront; Wo at [8E..) ----
    ushort* W3 = us + 6 * E;  // QKV W convs live in not-yet-used AO region
    ushort* Wqh = W3, *Wql = W3 + WE;
    ushort* Wkh = W3 + 2 * WE, *Wkl = W3 + 3 * WE;
    ushort* Wvh = W3 + 4 * WE, *Wvl = W3 + 5 * WE;
    ushort* Woh = us + 8 * E, *Wol = us + 8 * E + WE;  // survives attn
    ushort* AOh = us + 6 * E, *AOl = us + 7 * E;       // overwrites W3 later

    wconv4_kernel<<<4 * wgrid, blk, 0, stream>>>(Wq, Wk, Wv, Wo, Wqh, Wql, Wkh,
                                                 Wkl, Wvh, Wvl, Woh, Wol);
    qkv_proj_kernel<<<qgrid, blk, 0, stream>>>(q, k, v, Wqh, Wql, Wkh, Wkl,
                                               Wvh, Wvl, bq, bk, bv, Qh, Ql,
                                               Kh, Kl, Vth, Vtl);
    attn_mfma_kernel<true><<<agrid, blk, 0, stream>>>(Qh, Ql, Kh, Kl, Vth, Vtl,
                                                      nullptr, AOh, AOl);
    proj_mfma_kernel<3, true, true><<<pgrid, blk, 0, stream>>>(
        nullptr, AOh, AOl, nullptr, Woh, Wol, bo, out, nullptr, nullptr);
  } else if (ws_size >= 8 * E * sizeof(ushort)) {
    // ---- Tier A (ws >= 134.2 MB): r13 schedule with fused QKV launch ----
    ushort* W3 = us + 6 * E;
    ushort* Wqh = W3, *Wql = W3 + WE;
    ushort* Wkh = W3 + 2 * WE, *Wkl = W3 + 3 * WE;
    ushort* Wvh = W3 + 4 * WE, *Wvl = W3 + 5 * WE;
    ushort* AOh = us + 6 * E, *AOl = us + 7 * E;
    ushort* Woh = us, *Wol = us + WE;  // Qh region, dead post-attn

    wconv3_kernel<<<3 * wgrid, blk, 0, stream>>>(Wq, Wk, Wv, Wqh, Wql, Wkh,
                                                 Wkl, Wvh, Wvl);
    qkv_proj_kernel<<<qgrid, blk, 0, stream>>>(q, k, v, Wqh, Wql, Wkh, Wkl,
                                               Wvh, Wvl, bq, bk, bv, Qh, Ql,
                                               Kh, Kl, Vth, Vtl);
    attn_mfma_kernel<true><<<agrid, blk, 0, stream>>>(Qh, Ql, Kh, Kl, Vth, Vtl,
                                                      nullptr, AOh, AOl);
    wconv_kernel<<<wgrid, blk, 0, stream>>>(Wo, Woh, Wol);
    proj_mfma_kernel<3, true, true><<<pgrid, blk, 0, stream>>>(
        nullptr, AOh, AOl, nullptr, Woh, Wol, bo, out, nullptr, nullptr);
  } else if (ws_size >= (6 * E + 6 * WE) * sizeof(ushort)) {
    // ---- Tier B (ws >= 113.3 MB): AO hi/lo lives in `out` ----
    ushort* W3 = us + 6 * E;
    ushort* Wqh = W3, *Wql = W3 + WE;
    ushort* Wkh = W3 + 2 * WE, *Wkl = W3 + 3 * WE;
    ushort* Wvh = W3 + 4 * WE, *Wvl = W3 + 5 * WE;
    ushort* AOh = (ushort*)d_out, *AOl = AOh + E;
    ushort* Woh = us, *Wol = us + WE;
    float* PO = (float*)(us + 2 * E);

    wconv3_kernel<<<3 * wgrid, blk, 0, stream>>>(Wq, Wk, Wv, Wqh, Wql, Wkh,
                                                 Wkl, Wvh, Wvl);
    qkv_proj_kernel<<<qgrid, blk, 0, stream>>>(q, k, v, Wqh, Wql, Wkh, Wkl,
                                               Wvh, Wvl, bq, bk, bv, Qh, Ql,
                                               Kh, Kl, Vth, Vtl);
    attn_mfma_kernel<true><<<agrid, blk, 0, stream>>>(Qh, Ql, Kh, Kl, Vth, Vtl,
                                                      nullptr, AOh, AOl);
    wconv_kernel<<<wgrid, blk, 0, stream>>>(Wo, Woh, Wol);
    proj_mfma_kernel<3, true, true><<<pgrid, blk, 0, stream>>>(
        nullptr, AOh, AOl, nullptr, Woh, Wol, bo, PO, nullptr, nullptr);
    hipError_t e1 = hipMemcpyAsync(out, PO, E * sizeof(float),
                                   hipMemcpyDeviceToDevice, stream);
    (void)e1;
  } else {
    // ---- Tier C: in-kernel W conversion, fp32 AO (single-buffer legacy) ----
    float* AO = out;
    float* PO = (float*)d_ws;
    proj_mfma_kernel<0, false, false><<<pgrid, blk, 0, stream>>>(
        q, nullptr, nullptr, Wq, nullptr, nullptr, bq, nullptr, Qh, Ql);
    proj_mfma_kernel<1, false, false><<<pgrid, blk, 0, stream>>>(
        k, nullptr, nullptr, Wk, nullptr, nullptr, bk, nullptr, Kh, Kl);
    proj_mfma_kernel<2, false, false><<<pgrid, blk, 0, stream>>>(
        v, nullptr, nullptr, Wv, nullptr, nullptr, bv, nullptr, Vth, Vtl);
    attn_mfma_kernel<false><<<agrid, blk, 0, stream>>>(
        Qh, Ql, Kh, Kl, Vth, Vtl, AO, nullptr, nullptr);
    proj_mfma_kernel<3, false, false><<<pgrid, blk, 0, stream>>>(
        AO, nullptr, nullptr, Wo, nullptr, nullptr, bo, PO, nullptr, nullptr);
    hipError_t e2 = hipMemcpyAsync(out, PO, E * sizeof(float),
                                   hipMemcpyDeviceToDevice, stream);
    (void)e2;
  }
}